// Round 7
// baseline (16613.425 us; speedup 1.0000x reference)
//
#include <hip/hip_runtime.h>

typedef unsigned short u16;
typedef unsigned int u32;
typedef unsigned long long u64;
typedef __attribute__((ext_vector_type(8))) short bf16x8;
typedef __attribute__((ext_vector_type(4))) float f32x4;

#define S_LEN 5120
#define UB 64
#define GA 1152
#define CAPP (1 << 16)

__device__ __forceinline__ float bf2f(u16 u) { return __uint_as_float(((u32)u) << 16); }
__device__ __forceinline__ u16 f2bf(float f) {
    u32 x = __float_as_uint(f);
    return (u16)((x + 0x7fffu + ((x >> 16) & 1u)) >> 16);
}
__device__ __forceinline__ float sigm(float x) { return 1.f / (1.f + __expf(-x)); }
__device__ __forceinline__ float tanh_(float x) { float e = __expf(2.f * x); return 1.f - 2.f / (e + 1.f); }

__device__ __forceinline__ u64 ald64(const u64* p) {
    return __hip_atomic_load(p, __ATOMIC_RELAXED, __HIP_MEMORY_SCOPE_AGENT);
}
__device__ __forceinline__ u32 ald32(const u32* p) {
    return __hip_atomic_load(p, __ATOMIC_RELAXED, __HIP_MEMORY_SCOPE_AGENT);
}
__device__ __forceinline__ void ast32(u32* p, u32 v) {
    __hip_atomic_store(p, v, __ATOMIC_RELAXED, __HIP_MEMORY_SCOPE_AGENT);
}

// ---------------- convert grua_wih to bf16 ----------------
__global__ __launch_bounds__(256) void k_cvt(const float* __restrict__ src, u16* __restrict__ dst) {
    int i = blockIdx.x * 256 + threadIdx.x;
    dst[i] = f2bf(src[i]);
}

// ---------------- frame-rate network ----------------
__global__ __launch_bounds__(128) void k_frame1(const float* __restrict__ features, const int* __restrict__ periods,
                                                const float* __restrict__ pemb, const float* __restrict__ w,
                                                const float* __restrict__ bias, float* __restrict__ c1) {
    __shared__ float fin[3][84];
    int t = blockIdx.x, b = blockIdx.y, o = threadIdx.x;
    for (int i = threadIdx.x; i < 252; i += 128) {
        int kk = i / 84, ci = i % 84, tt = t + kk;
        float v;
        if (ci < 20) v = features[(b * 36 + tt) * 20 + ci];
        else v = pemb[periods[b * 36 + tt] * 64 + (ci - 20)];
        fin[kk][ci] = v;
    }
    __syncthreads();
    float acc = bias[o];
    for (int kk = 0; kk < 3; kk++)
        for (int ci = 0; ci < 84; ci++)
            acc = fmaf(fin[kk][ci], w[o * 252 + ci * 3 + kk], acc);
    c1[(b * 34 + t) * 128 + o] = tanh_(acc);
}

__global__ __launch_bounds__(128) void k_frame2(const float* __restrict__ c1, const float* __restrict__ w,
                                                const float* __restrict__ bias, float* __restrict__ c2) {
    __shared__ float fin[3][128];
    int t = blockIdx.x, b = blockIdx.y, o = threadIdx.x;
    for (int i = threadIdx.x; i < 384; i += 128) {
        int kk = i >> 7, ci = i & 127;
        fin[kk][ci] = c1[(b * 34 + t + kk) * 128 + ci];
    }
    __syncthreads();
    float acc = bias[o];
    for (int kk = 0; kk < 3; kk++)
        for (int ci = 0; ci < 128; ci++)
            acc = fmaf(fin[kk][ci], w[o * 384 + ci * 3 + kk], acc);
    c2[(b * 32 + t) * 128 + o] = tanh_(acc);
}

__global__ __launch_bounds__(128) void k_fd(const float* __restrict__ c2, const float* __restrict__ w1,
                                            const float* __restrict__ b1, const float* __restrict__ w2,
                                            const float* __restrict__ b2, float* __restrict__ cc) {
    __shared__ float a0[128], a1s[128];
    int t = blockIdx.x, b = blockIdx.y, o = threadIdx.x;
    a0[o] = c2[(b * 32 + t) * 128 + o];
    __syncthreads();
    float acc = b1[o];
    for (int k = 0; k < 128; k++) acc = fmaf(a0[k], w1[o * 128 + k], acc);
    a1s[o] = tanh_(acc);
    __syncthreads();
    float acc2 = b2[o];
    for (int k = 0; k < 128; k++) acc2 = fmaf(a1s[k], w2[o * 128 + k], acc2);
    cc[(b * 32 + t) * 128 + o] = tanh_(acc2);
}

// cpart[b][fr][192] = grub_wih[:,384:512] @ c[b][fr] + grub_bih
__global__ __launch_bounds__(192) void k_cpart(const float* __restrict__ cc, const float* __restrict__ wihB,
                                               const float* __restrict__ bihB, float* __restrict__ cpart) {
    __shared__ float cl[128];
    int fr = blockIdx.x, b = blockIdx.y, o = threadIdx.x;
    if (o < 128) cl[o] = cc[(b * 32 + fr) * 128 + o];
    __syncthreads();
    float acc = bihB[o];
    for (int k = 0; k < 128; k++) acc = fmaf(cl[k], wihB[o * 512 + 384 + k], acc);
    cpart[((size_t)b * 32 + fr) * 192 + o] = acc;
}

// ---------------- init: slot 7 of ring with h0a tags 0 + bprog=0 ----------------
__global__ __launch_bounds__(256) void k_init2(const float* __restrict__ h0a, u32* ring, u32* bprog) {
    int i = blockIdx.x * 256 + threadIdx.x;  // 0..6143
    int s = i >> 9, idx = i & 511;
    int b = idx >> 5, u = idx & 31;
    ring[(size_t)7 * 12 * 512 + i] = ((u32)f2bf(h0a[b * 384 + 32 * s + u]) << 16);
    if (i == 0) *bprog = 0u;
}

// ---------------- GRU-A input projection GEMM (writes PERMUTED xpT) ----------------
// pcol = slice*96 + gate*32 + unit  where col = gate*384 + 32*slice + unit
__global__ __launch_bounds__(256) void k_gemm(const int* __restrict__ signals, const float* __restrict__ semb,
                                              const float* __restrict__ c, const u16* __restrict__ wih,
                                              const float* __restrict__ bih, u16* __restrict__ xpT) {
    __shared__ u16 As[64][40];
    __shared__ u16 Bs[64][40];
    int m0 = blockIdx.x * 64, n0 = blockIdx.y * 64;
    int tid = threadIdx.x;
    int r = tid >> 2, kc = tid & 3;
    int lane = tid & 63, wv = tid >> 6;
    int wr = wv >> 1, wc = wv & 1;
    int mrow = m0 + r;
    int b = mrow / S_LEN, s = mrow % S_LEN;
    const int* sigrow = signals + mrow * 3;
    const float* crow = c + ((size_t)(b * 32) + s / 160) * 128;
    f32x4 acc[2][2];
#pragma unroll
    for (int i = 0; i < 2; i++)
#pragma unroll
        for (int j = 0; j < 2; j++) { acc[i][j][0] = 0.f; acc[i][j][1] = 0.f; acc[i][j][2] = 0.f; acc[i][j][3] = 0.f; }
    for (int k0 = 0; k0 < 512; k0 += 32) {
        int k = k0 + kc * 8;
        float v[8];
        if (k < 384) {
            int idx = sigrow[k >> 7];
            const float* src = semb + idx * 128 + (k & 127);
#pragma unroll
            for (int j = 0; j < 8; j++) v[j] = src[j];
        } else {
            const float* src = crow + (k - 384);
#pragma unroll
            for (int j = 0; j < 8; j++) v[j] = src[j];
        }
        u32 pk[4];
#pragma unroll
        for (int j = 0; j < 4; j++) pk[j] = (u32)f2bf(v[2 * j]) | ((u32)f2bf(v[2 * j + 1]) << 16);
        *(uint4*)&As[r][kc * 8] = *(uint4*)pk;
        *(uint4*)&Bs[r][kc * 8] = *(const uint4*)&wih[(size_t)(n0 + r) * 512 + k];
        __syncthreads();
        bf16x8 af[2], bfr[2];
#pragma unroll
        for (int mi = 0; mi < 2; mi++) af[mi] = *(const bf16x8*)&As[wr * 32 + mi * 16 + (lane & 15)][(lane >> 4) * 8];
#pragma unroll
        for (int ni = 0; ni < 2; ni++) bfr[ni] = *(const bf16x8*)&Bs[wc * 32 + ni * 16 + (lane & 15)][(lane >> 4) * 8];
#pragma unroll
        for (int mi = 0; mi < 2; mi++)
#pragma unroll
            for (int ni = 0; ni < 2; ni++)
                acc[mi][ni] = __builtin_amdgcn_mfma_f32_16x16x32_bf16(af[mi], bfr[ni], acc[mi][ni], 0, 0, 0);
        __syncthreads();
    }
#pragma unroll
    for (int mi = 0; mi < 2; mi++)
#pragma unroll
        for (int ni = 0; ni < 2; ni++) {
            int row = m0 + wr * 32 + mi * 16 + (lane >> 4) * 4;
            int col = n0 + wc * 32 + ni * 16 + (lane & 15);
            int g = col / 384, uu = col - g * 384;
            int pcol = (uu >> 5) * 96 + g * 32 + (uu & 31);
            float bias = bih[col];
#pragma unroll
            for (int i = 0; i < 4; i++)
                xpT[(size_t)(row + i) * GA + pcol] = f2bf(acc[mi][ni][i] + bias);
        }
}

// ---------------- fused-batch serial GRU: 12 A-WGs + 1 B-WG, one exchange domain ----------------
// ring u32[8 slots][12 slices][512]  word = (bf16(h)<<16) | (t+1) ; value idx = b*32+u
struct SA_t {
    u16 hA16[2][16][392];   // bf16 h image, parity; col = global unit
    u16 xpb[2][16][96];     // xp slice, parity; [b][g*32+u]
    float pre[96][17];      // [j][batch]
};
struct SB_t {
    u16 hA16[16][392];      // single buffer
    u16 hB16[2][16][72];
    float preY[192][17];
    float preH[192][17];
};
union SMemU { SA_t a; SB_t b; };

__global__ __launch_bounds__(512, 1) void k_serial(
        const float* __restrict__ whhA, const float* __restrict__ bhhA,
        const float* __restrict__ wihB, const float* __restrict__ whhB,
        const float* __restrict__ bhhB, const u16* __restrict__ xpT,
        const float* __restrict__ cpart, const float* __restrict__ h0a,
        const float* __restrict__ h0b, u32* ring, u32* bprog,
        float* __restrict__ yB) {
    __shared__ SMemU sm;
    __shared__ int dead;
    const int blk = blockIdx.x, tid = threadIdx.x;
    const int lane = tid & 63, wv = tid >> 6;

    if (blk < 12) {
        // ================= A-WG: slice s = units 32s..32s+31 (x3 gates) =================
        SA_t& S = sm.a;
        const int s = blk;
        // b-fragments in VGPRs: wave wv<6 owns N-tile wv (j = 16wv..16wv+15)
        bf16x8 wfrag[12];
        if (wv < 6) {
            int j = wv * 16 + (lane & 15);
            int R = (j >> 5) * 384 + 32 * s + (j & 31);
            const float* wr = whhA + (size_t)R * 384 + (lane >> 4) * 8;
#pragma unroll
            for (int K = 0; K < 12; K++)
#pragma unroll
                for (int jj = 0; jj < 8; jj++) wfrag[K][jj] = (short)f2bf(wr[K * 32 + jj]);
        }
        const int gb = tid >> 5, gu = tid & 31;  // gate task (batch, unit)
        const float bias0 = bhhA[32 * s + gu];
        const float bias1 = bhhA[384 + 32 * s + gu];
        const float bias2 = bhhA[768 + 32 * s + gu];
        float hpr = h0a[gb * 384 + 32 * s + gu];
        for (int v = tid; v < 6144; v += 512) {
            int b = v / 384, col = v - b * 384;
            S.hA16[0][b][col] = f2bf(h0a[v]);
        }
        for (int v = tid; v < 1536; v += 512) {
            int b = v / 96, j = v - b * 96;
            S.xpb[0][b][j] = xpT[((size_t)b * S_LEN) * GA + s * 96 + j];
        }
        if (tid == 0) dead = 0;
        __syncthreads();

        const int pb = tid / 24, pj = (tid % 24) * 4;
        for (int t = 0; t < S_LEN; ++t) {
            const int p = t & 1, p2 = p ^ 1;
            // xp(t+1) prefetch issue
            uint2 xpf = make_uint2(0, 0);
            const bool hasx = (tid < 384) && (t + 1 < S_LEN);
            if (hasx) xpf = *(const uint2*)&xpT[((size_t)(pb * S_LEN + t + 1)) * GA + s * 96 + pj];
            // poll remote 11 slices of h(t-1): 2816 u64, strided 6/thread
            if (t > 0) {
                const u64* rb = (const u64*)ring + (size_t)((t - 1) & 7) * 12 * 256;
                const u32 tg = (u32)t;
                u64 v[6]; bool ok[6]; const u64* ap[6];
#pragma unroll
                for (int i = 0; i < 6; i++) {
                    int w = i * 512 + tid;
                    bool act = w < 2816;
                    int ps = w >> 8; ps += (ps >= s);
                    ap[i] = rb + ps * 256 + (w & 255);
                    v[i] = act ? ald64(ap[i]) : 0;
                    ok[i] = !act;
                }
                for (int round = 0;; ++round) {
                    bool all = true;
#pragma unroll
                    for (int i = 0; i < 6; i++)
                        if (!ok[i]) {
                            ok[i] = (((u32)v[i] & 0xffffu) == tg) && (((u32)(v[i] >> 32) & 0xffffu) == tg);
                            all = all && ok[i];
                        }
                    if (all) break;
                    if (dead || round > CAPP) { dead = 1; break; }
                    if (round >= 2) __builtin_amdgcn_s_sleep(2);
#pragma unroll
                    for (int i = 0; i < 6; i++) if (!ok[i]) v[i] = ald64(ap[i]);
                }
#pragma unroll
                for (int i = 0; i < 6; i++) {
                    int w = i * 512 + tid;
                    if (w < 2816) {
                        int ps = w >> 8; ps += (ps >= s);
                        int idx2 = (w & 255) * 2;
                        int b = idx2 >> 5, u = idx2 & 31;
                        u32 pair = ((u32)v[i] >> 16) | ((u32)(v[i] >> 32) & 0xffff0000u);
                        *(u32*)&S.hA16[p][b][32 * ps + u] = pair;
                    }
                }
                if (tid == 0 && t >= 7) {
                    int cnt = 0;
                    while ((int)ald32(bprog) < t - 6) {
                        if (dead || ++cnt > CAPP) { dead = 1; break; }
                    }
                }
            }
            __syncthreads();  // S1: hA16[p] complete
            // MFMA: D(16x96) = h(16x384) @ W_slice
            if (wv < 6) {
                bf16x8 af[12];
#pragma unroll
                for (int K = 0; K < 12; K++)
                    af[K] = *(const bf16x8*)&S.hA16[p][lane & 15][K * 32 + (lane >> 4) * 8];
                f32x4 acc = {0.f, 0.f, 0.f, 0.f};
#pragma unroll
                for (int K = 0; K < 12; K++)
                    acc = __builtin_amdgcn_mfma_f32_16x16x32_bf16(af[K], wfrag[K], acc, 0, 0, 0);
#pragma unroll
                for (int i = 0; i < 4; i++)
                    S.pre[wv * 16 + (lane & 15)][(lane >> 4) * 4 + i] = acc[i];
            }
            __syncthreads();  // S2: pre ready
            // gates (1 task/thread) + publish
            {
                float pr = S.pre[gu][gb] + bias0;
                float pz = S.pre[32 + gu][gb] + bias1;
                float pn = S.pre[64 + gu][gb] + bias2;
                float rg = sigm(bf2f(S.xpb[p][gb][gu]) + pr);
                float zg = sigm(bf2f(S.xpb[p][gb][32 + gu]) + pz);
                float ng = tanh_(bf2f(S.xpb[p][gb][64 + gu]) + rg * pn);
                float hnew = (1.f - zg) * ng + zg * hpr;
                hpr = hnew;
                u16 hb = f2bf(hnew);
                S.hA16[p2][gb][32 * s + gu] = hb;
                ast32(ring + (size_t)(t & 7) * 12 * 512 + s * 512 + tid, ((u32)hb << 16) | (u32)(t + 1));
            }
            if (hasx) *(uint2*)&S.xpb[p2][pb][pj] = xpf;
            // no trailing barrier: next S1 orders everything (disjoint LDS writes meanwhile)
        }
    } else {
        // ================= B-WG: all 64 GRU-B units x 16 batches, hB local =================
        SB_t& S = sm.b;
        bf16x8 wyf[2][12], whf[2][2];
        const int ntn = (wv < 4) ? 2 : 1;
#pragma unroll
        for (int tt = 0; tt < 2; tt++) {
            if (tt < ntn) {
                int j = (tt == 0 ? wv : wv + 8) * 16 + (lane & 15);  // row R = j (torch layout)
                const float* wr = wihB + (size_t)j * 512 + (lane >> 4) * 8;
#pragma unroll
                for (int K = 0; K < 12; K++)
#pragma unroll
                    for (int jj = 0; jj < 8; jj++) wyf[tt][K][jj] = (short)f2bf(wr[K * 32 + jj]);
                const float* wr2 = whhB + (size_t)j * 64 + (lane >> 4) * 8;
#pragma unroll
                for (int K = 0; K < 2; K++)
#pragma unroll
                    for (int jj = 0; jj < 8; jj++) whf[tt][K][jj] = (short)f2bf(wr2[K * 32 + jj]);
            }
        }
        const int Bu = tid & 63, Bp = tid >> 6;
        const float bB0 = bhhB[Bu], bB1 = bhhB[64 + Bu], bB2 = bhhB[128 + Bu];
        float hprB0 = h0b[(2 * Bp) * 64 + Bu];
        float hprB1 = h0b[(2 * Bp + 1) * 64 + Bu];
        S.hB16[0][2 * Bp][Bu] = f2bf(hprB0);
        S.hB16[0][2 * Bp + 1][Bu] = f2bf(hprB1);
        if (tid == 0) dead = 0;
        __syncthreads();

        for (int t = 0; t < S_LEN; ++t) {
            const int p = t & 1, p2 = p ^ 1;
            // poll full hA(t): 3072 u64, 6/thread strided; tag t+1, slot t&7
            {
                const u64* rb = (const u64*)ring + (size_t)(t & 7) * 12 * 256;
                const u32 tg = (u32)(t + 1);
                u64 v[6]; bool ok[6];
#pragma unroll
                for (int i = 0; i < 6; i++) { v[i] = ald64(rb + i * 512 + tid); ok[i] = false; }
                for (int round = 0;; ++round) {
                    bool all = true;
#pragma unroll
                    for (int i = 0; i < 6; i++)
                        if (!ok[i]) {
                            ok[i] = (((u32)v[i] & 0xffffu) == tg) && (((u32)(v[i] >> 32) & 0xffffu) == tg);
                            all = all && ok[i];
                        }
                    if (all) break;
                    if (dead || round > CAPP) { dead = 1; break; }
                    if (round >= 2) __builtin_amdgcn_s_sleep(2);
#pragma unroll
                    for (int i = 0; i < 6; i++) if (!ok[i]) v[i] = ald64(rb + i * 512 + tid);
                }
#pragma unroll
                for (int i = 0; i < 6; i++) {
                    int w = i * 512 + tid;
                    int ps = w >> 8, idx2 = (w & 255) * 2;
                    int b = idx2 >> 5, u = idx2 & 31;
                    u32 pair = ((u32)v[i] >> 16) | ((u32)(v[i] >> 32) & 0xffff0000u);
                    *(u32*)&S.hA16[b][32 * ps + u] = pair;
                }
            }
            __syncthreads();  // S1
            // MFMA: D_y(16x192) = hA @ wihB^T ; D_h(16x192) = hB @ whhB^T
            {
                bf16x8 af[12];
#pragma unroll
                for (int K = 0; K < 12; K++)
                    af[K] = *(const bf16x8*)&S.hA16[lane & 15][K * 32 + (lane >> 4) * 8];
                bf16x8 ab0 = *(const bf16x8*)&S.hB16[p][lane & 15][(lane >> 4) * 8];
                bf16x8 ab1 = *(const bf16x8*)&S.hB16[p][lane & 15][32 + (lane >> 4) * 8];
#pragma unroll
                for (int tt = 0; tt < 2; tt++) {
                    if (tt < ntn) {
                        f32x4 acc = {0.f, 0.f, 0.f, 0.f};
#pragma unroll
                        for (int K = 0; K < 12; K++)
                            acc = __builtin_amdgcn_mfma_f32_16x16x32_bf16(af[K], wyf[tt][K], acc, 0, 0, 0);
                        f32x4 acch = {0.f, 0.f, 0.f, 0.f};
                        acch = __builtin_amdgcn_mfma_f32_16x16x32_bf16(ab0, whf[tt][0], acch, 0, 0, 0);
                        acch = __builtin_amdgcn_mfma_f32_16x16x32_bf16(ab1, whf[tt][1], acch, 0, 0, 0);
                        int jb = (tt == 0 ? wv : wv + 8) * 16 + (lane & 15);
#pragma unroll
                        for (int i = 0; i < 4; i++) {
                            S.preY[jb][(lane >> 4) * 4 + i] = acc[i];
                            S.preH[jb][(lane >> 4) * 4 + i] = acch[i];
                        }
                    }
                }
            }
            __syncthreads();  // S2
            // gates x2 tasks
            const int fr = t / 160;
#pragma unroll
            for (int i = 0; i < 2; i++) {
                int b = 2 * Bp + i;
                float hprB = i ? hprB1 : hprB0;
                const float* cp = cpart + ((size_t)b * 32 + fr) * 192;
                float xr = S.preY[Bu][b] + cp[Bu];
                float xz = S.preY[64 + Bu][b] + cp[64 + Bu];
                float xn = S.preY[128 + Bu][b] + cp[128 + Bu];
                float hr = S.preH[Bu][b] + bB0;
                float hz = S.preH[64 + Bu][b] + bB1;
                float hn = S.preH[128 + Bu][b] + bB2;
                float rg = sigm(xr + hr);
                float zg = sigm(xz + hz);
                float ng = tanh_(xn + rg * hn);
                float hnew = (1.f - zg) * ng + zg * hprB;
                if (i) hprB1 = hnew; else hprB0 = hnew;
                yB[((size_t)b * S_LEN + t) * UB + Bu] = hnew;
                S.hB16[p2][b][Bu] = f2bf(hnew);
            }
            if (tid == 0) ast32(bprog, (u32)(t + 1));
        }
    }
}

// ---------------- dual FC + log_softmax ----------------
__global__ __launch_bounds__(256) void k_fc(const float* __restrict__ yB, const float* __restrict__ w1,
                                            const float* __restrict__ b1, const float* __restrict__ w2,
                                            const float* __restrict__ b2, const float* __restrict__ alpha,
                                            const float* __restrict__ beta, float* __restrict__ out) {
    __shared__ float yb[4][64];
    __shared__ float vb[4][256];
    int tid = threadIdx.x;
    size_t r0 = (size_t)blockIdx.x * 4;
    { int r = tid >> 6, k = tid & 63; yb[r][k] = yB[(r0 + r) * 64 + k]; }
    __syncthreads();
    int o = tid;
    float a1[4] = {0, 0, 0, 0}, a2[4] = {0, 0, 0, 0};
    for (int k = 0; k < 64; k += 4) {
        float4 u = *(const float4*)(w1 + o * 64 + k);
        float4 v = *(const float4*)(w2 + o * 64 + k);
#pragma unroll
        for (int r = 0; r < 4; r++) {
            float y0 = yb[r][k], y1 = yb[r][k + 1], y2 = yb[r][k + 2], y3 = yb[r][k + 3];
            a1[r] = fmaf(u.x, y0, fmaf(u.y, y1, fmaf(u.z, y2, fmaf(u.w, y3, a1[r]))));
            a2[r] = fmaf(v.x, y0, fmaf(v.y, y1, fmaf(v.z, y2, fmaf(v.w, y3, a2[r]))));
        }
    }
    float al = alpha[o], be = beta[o], c1 = b1[o], c2 = b2[o];
#pragma unroll
    for (int r = 0; r < 4; r++)
        vb[r][o] = al * tanh_(a1[r] + c1) + be * tanh_(a2[r] + c2);
    __syncthreads();
    int wv = tid >> 6, l = tid & 63;
    float x0 = vb[wv][l], x1 = vb[wv][64 + l], x2 = vb[wv][128 + l], x3 = vb[wv][192 + l];
    float m = fmaxf(fmaxf(x0, x1), fmaxf(x2, x3));
#pragma unroll
    for (int off = 1; off < 64; off <<= 1) m = fmaxf(m, __shfl_xor(m, off));
    float sum = __expf(x0 - m) + __expf(x1 - m) + __expf(x2 - m) + __expf(x3 - m);
#pragma unroll
    for (int off = 1; off < 64; off <<= 1) sum += __shfl_xor(sum, off);
    float lse = m + __logf(sum);
    float* po = out + (r0 + wv) * 256;
    po[l] = x0 - lse;
    po[64 + l] = x1 - lse;
    po[128 + l] = x2 - lse;
    po[192 + l] = x3 - lse;
}

extern "C" void kernel_launch(void* const* d_in, const int* in_sizes, int n_in,
                              void* d_out, int out_size, void* d_ws, size_t ws_size,
                              hipStream_t stream) {
    const float* features = (const float*)d_in[0];
    const int* periods = (const int*)d_in[1];
    const int* signals = (const int*)d_in[2];
    const float* gruA0 = (const float*)d_in[3];
    const float* gruB0 = (const float*)d_in[4];
    const float* period_emb = (const float*)d_in[5];
    const float* signal_emb = (const float*)d_in[6];
    const float* conv1_w = (const float*)d_in[7];
    const float* conv1_b = (const float*)d_in[8];
    const float* conv2_w = (const float*)d_in[9];
    const float* conv2_b = (const float*)d_in[10];
    const float* fd1_w = (const float*)d_in[11];
    const float* fd1_b = (const float*)d_in[12];
    const float* fd2_w = (const float*)d_in[13];
    const float* fd2_b = (const float*)d_in[14];
    const float* grua_wih = (const float*)d_in[15];
    const float* grua_whh = (const float*)d_in[16];
    const float* grua_bih = (const float*)d_in[17];
    const float* grua_bhh = (const float*)d_in[18];
    const float* grub_wih = (const float*)d_in[19];
    const float* grub_whh = (const float*)d_in[20];
    const float* grub_bih = (const float*)d_in[21];
    const float* grub_bhh = (const float*)d_in[22];
    const float* fc1_w = (const float*)d_in[23];
    const float* fc1_b = (const float*)d_in[24];
    const float* fc2_w = (const float*)d_in[25];
    const float* fc2_b = (const float*)d_in[26];
    const float* alpha = (const float*)d_in[27];
    const float* beta = (const float*)d_in[28];
    float* out = (float*)d_out;

    char* ws = (char*)d_ws;
    size_t off = 0;
    auto alloc = [&](size_t bytes) { void* p = ws + off; off += (bytes + 255) & ~(size_t)255; return p; };
    u16* xpT = (u16*)alloc((size_t)16 * 5120 * 1152 * 2);
    u16* wihA = (u16*)alloc((size_t)1152 * 512 * 2);
    float* c1 = (float*)alloc((size_t)16 * 34 * 128 * 4);
    float* c2 = (float*)alloc((size_t)16 * 32 * 128 * 4);
    float* cc = (float*)alloc((size_t)16 * 32 * 128 * 4);
    float* cpart = (float*)alloc((size_t)16 * 32 * 192 * 4);
    float* yB = (float*)alloc((size_t)16 * 5120 * 64 * 4);
    u32* ring = (u32*)alloc((size_t)(8 * 12 * 512 + 64) * 4);
    u32* bprog = ring + 8 * 12 * 512;

    k_cvt<<<dim3(2304), dim3(256), 0, stream>>>(grua_wih, wihA);
    k_frame1<<<dim3(34, 16), dim3(128), 0, stream>>>(features, periods, period_emb, conv1_w, conv1_b, c1);
    k_frame2<<<dim3(32, 16), dim3(128), 0, stream>>>(c1, conv2_w, conv2_b, c2);
    k_fd<<<dim3(32, 16), dim3(128), 0, stream>>>(c2, fd1_w, fd1_b, fd2_w, fd2_b, cc);
    k_cpart<<<dim3(32, 16), dim3(192), 0, stream>>>(cc, grub_wih, grub_bih, cpart);
    k_init2<<<dim3(24), dim3(256), 0, stream>>>(gruA0, ring, bprog);
    k_gemm<<<dim3(1280, 18), dim3(256), 0, stream>>>(signals, signal_emb, cc, wihA, grua_bih, xpT);
    k_serial<<<dim3(13), dim3(512), 0, stream>>>(grua_whh, grua_bhh, grub_wih, grub_whh, grub_bhh,
                                                 xpT, cpart, gruA0, gruB0, ring, bprog, yB);
    k_fc<<<dim3(20480), dim3(256), 0, stream>>>(yB, fc1_w, fc1_b, fc2_w, fc2_b, alpha, beta, out);
}

// Round 8
// 12194.104 us; speedup vs baseline: 1.3624x; 1.3624x over previous
//
#include <hip/hip_runtime.h>

typedef unsigned short u16;
typedef unsigned int u32;
typedef unsigned long long u64;
typedef __attribute__((ext_vector_type(8))) short bf16x8;
typedef __attribute__((ext_vector_type(4))) float f32x4;

#define S_LEN 5120
#define UB 64
#define GA 1152
#define CAPP (1 << 16)
#define FASTCAP 20000

__device__ __forceinline__ float bf2f(u16 u) { return __uint_as_float(((u32)u) << 16); }
__device__ __forceinline__ u16 f2bf(float f) {
    u32 x = __float_as_uint(f);
    return (u16)((x + 0x7fffu + ((x >> 16) & 1u)) >> 16);
}
__device__ __forceinline__ float blo(u32 w) { return __uint_as_float(w << 16); }
__device__ __forceinline__ float bhi(u32 w) { return __uint_as_float(w & 0xffff0000u); }
__device__ __forceinline__ float sigm(float x) { return 1.f / (1.f + __expf(-x)); }
__device__ __forceinline__ float tanh_(float x) { float e = __expf(2.f * x); return 1.f - 2.f / (e + 1.f); }

#if __has_builtin(__builtin_amdgcn_fdot2)
typedef _Float16 h2v __attribute__((ext_vector_type(2)));
__device__ __forceinline__ float dot2p(u32 w, u32 h, float acc) {
    return __builtin_amdgcn_fdot2(__builtin_bit_cast(h2v, w), __builtin_bit_cast(h2v, h), acc, false);
}
__device__ __forceinline__ u32 packpair(float a, float b) {
    u16 x = __builtin_bit_cast(u16, (_Float16)a);
    u16 y = __builtin_bit_cast(u16, (_Float16)b);
    return (u32)x | ((u32)y << 16);
}
__device__ __forceinline__ u16 pack1(float a) { return __builtin_bit_cast(u16, (_Float16)a); }
#else
__device__ __forceinline__ float dot2p(u32 w, u32 h, float acc) {
    acc = fmaf(blo(w), blo(h), acc);
    return fmaf(bhi(w), bhi(h), acc);
}
__device__ __forceinline__ u32 packpair(float a, float b) { return (u32)f2bf(a) | ((u32)f2bf(b) << 16); }
__device__ __forceinline__ u16 pack1(float a) { return f2bf(a); }
#endif

__device__ __forceinline__ u64 ald64(const u64* p) {
    return __hip_atomic_load(p, __ATOMIC_RELAXED, __HIP_MEMORY_SCOPE_AGENT);
}
__device__ __forceinline__ u32 ald32(const u32* p) {
    return __hip_atomic_load(p, __ATOMIC_RELAXED, __HIP_MEMORY_SCOPE_AGENT);
}
__device__ __forceinline__ void ast32(u32* p, u32 v) {
    __hip_atomic_store(p, v, __ATOMIC_RELAXED, __HIP_MEMORY_SCOPE_AGENT);
}
// L1-bypassing L2-hitting load (same-XCD fast path)
__device__ __forceinline__ u64 ld64_sc0(const u64* p) {
    u64 v;
    asm volatile("global_load_dwordx2 %0, %1, off sc0\n\ts_waitcnt vmcnt(0)"
                 : "=v"(v) : "v"(p) : "memory");
    return v;
}
__device__ __forceinline__ void st32_sc0(u32* p, u32 v) {
    asm volatile("global_store_dword %0, %1, off sc0" :: "v"(p), "v"(v) : "memory");
}
// publish: L2 path + L3 path (value identical; consumers pick whichever they can see)
__device__ __forceinline__ void pub32(u32* p, u32 v) {
    st32_sc0(p, v);
    ast32(p, v);
}
__device__ __forceinline__ u64 poll64(const u64* p, u32 tg, int* fastEn, int* dead) {
    u64 v;
    if (*fastEn) {
        for (int i = 0; i < FASTCAP; ++i) {
            v = ld64_sc0(p);
            if (((u32)v & 0xffffu) == tg && (((u32)(v >> 32)) & 0xffffu) == tg) return v;
        }
        *fastEn = 0;  // placement assumption failed for this WG: degrade permanently
    }
    int cnt = 0;
    for (;;) {
        v = ald64(p);
        if (((u32)v & 0xffffu) == tg && (((u32)(v >> 32)) & 0xffffu) == tg) return v;
        if (*dead || ++cnt > CAPP) { *dead = 1; return v; }
    }
}

// ---------------- convert grua_wih to bf16 ----------------
__global__ __launch_bounds__(256) void k_cvt(const float* __restrict__ src, u16* __restrict__ dst) {
    int i = blockIdx.x * 256 + threadIdx.x;
    dst[i] = f2bf(src[i]);
}

// ---------------- frame-rate network ----------------
__global__ __launch_bounds__(128) void k_frame1(const float* __restrict__ features, const int* __restrict__ periods,
                                                const float* __restrict__ pemb, const float* __restrict__ w,
                                                const float* __restrict__ bias, float* __restrict__ c1) {
    __shared__ float fin[3][84];
    int t = blockIdx.x, b = blockIdx.y, o = threadIdx.x;
    for (int i = threadIdx.x; i < 252; i += 128) {
        int kk = i / 84, ci = i % 84, tt = t + kk;
        float v;
        if (ci < 20) v = features[(b * 36 + tt) * 20 + ci];
        else v = pemb[periods[b * 36 + tt] * 64 + (ci - 20)];
        fin[kk][ci] = v;
    }
    __syncthreads();
    float acc = bias[o];
    for (int kk = 0; kk < 3; kk++)
        for (int ci = 0; ci < 84; ci++)
            acc = fmaf(fin[kk][ci], w[o * 252 + ci * 3 + kk], acc);
    c1[(b * 34 + t) * 128 + o] = tanh_(acc);
}

__global__ __launch_bounds__(128) void k_frame2(const float* __restrict__ c1, const float* __restrict__ w,
                                                const float* __restrict__ bias, float* __restrict__ c2) {
    __shared__ float fin[3][128];
    int t = blockIdx.x, b = blockIdx.y, o = threadIdx.x;
    for (int i = threadIdx.x; i < 384; i += 128) {
        int kk = i >> 7, ci = i & 127;
        fin[kk][ci] = c1[(b * 34 + t + kk) * 128 + ci];
    }
    __syncthreads();
    float acc = bias[o];
    for (int kk = 0; kk < 3; kk++)
        for (int ci = 0; ci < 128; ci++)
            acc = fmaf(fin[kk][ci], w[o * 384 + ci * 3 + kk], acc);
    c2[(b * 32 + t) * 128 + o] = tanh_(acc);
}

__global__ __launch_bounds__(128) void k_fd(const float* __restrict__ c2, const float* __restrict__ w1,
                                            const float* __restrict__ b1, const float* __restrict__ w2,
                                            const float* __restrict__ b2, float* __restrict__ cc) {
    __shared__ float a0[128], a1s[128];
    int t = blockIdx.x, b = blockIdx.y, o = threadIdx.x;
    a0[o] = c2[(b * 32 + t) * 128 + o];
    __syncthreads();
    float acc = b1[o];
    for (int k = 0; k < 128; k++) acc = fmaf(a0[k], w1[o * 128 + k], acc);
    a1s[o] = tanh_(acc);
    __syncthreads();
    float acc2 = b2[o];
    for (int k = 0; k < 128; k++) acc2 = fmaf(a1s[k], w2[o * 128 + k], acc2);
    cc[(b * 32 + t) * 128 + o] = tanh_(acc2);
}

// cpart[b][fr][192] = grub_wih[:,384:512] @ c[b][fr] + grub_bih
__global__ __launch_bounds__(192) void k_cpart(const float* __restrict__ cc, const float* __restrict__ wihB,
                                               const float* __restrict__ bihB, float* __restrict__ cpart) {
    __shared__ float cl[128];
    int fr = blockIdx.x, b = blockIdx.y, o = threadIdx.x;
    if (o < 128) cl[o] = cc[(b * 32 + fr) * 128 + o];
    __syncthreads();
    float acc = bihB[o];
    for (int k = 0; k < 128; k++) acc = fmaf(cl[k], wihB[o * 512 + 384 + k], acc);
    cpart[((size_t)b * 32 + fr) * 192 + o] = acc;
}

// ---------------- init: clear ring + bprog ----------------
__global__ __launch_bounds__(256) void k_init(u32* hEx) {
    hEx[blockIdx.x * 256 + threadIdx.x] = 0u;
}

// ---------------- GRU-A input projection GEMM ----------------
__global__ __launch_bounds__(256) void k_gemm(const int* __restrict__ signals, const float* __restrict__ semb,
                                              const float* __restrict__ c, const u16* __restrict__ wih,
                                              const float* __restrict__ bih, u16* __restrict__ xp) {
    __shared__ u16 As[64][40];
    __shared__ u16 Bs[64][40];
    int m0 = blockIdx.x * 64, n0 = blockIdx.y * 64;
    int tid = threadIdx.x;
    int r = tid >> 2, kc = tid & 3;
    int lane = tid & 63, wv = tid >> 6;
    int wr = wv >> 1, wc = wv & 1;
    int mrow = m0 + r;
    int b = mrow / S_LEN, s = mrow % S_LEN;
    const int* sigrow = signals + mrow * 3;
    const float* crow = c + ((size_t)(b * 32) + s / 160) * 128;
    f32x4 acc[2][2];
#pragma unroll
    for (int i = 0; i < 2; i++)
#pragma unroll
        for (int j = 0; j < 2; j++) { acc[i][j][0] = 0.f; acc[i][j][1] = 0.f; acc[i][j][2] = 0.f; acc[i][j][3] = 0.f; }
    for (int k0 = 0; k0 < 512; k0 += 32) {
        int k = k0 + kc * 8;
        float v[8];
        if (k < 384) {
            int idx = sigrow[k >> 7];
            const float* src = semb + idx * 128 + (k & 127);
#pragma unroll
            for (int j = 0; j < 8; j++) v[j] = src[j];
        } else {
            const float* src = crow + (k - 384);
#pragma unroll
            for (int j = 0; j < 8; j++) v[j] = src[j];
        }
        u32 pk[4];
#pragma unroll
        for (int j = 0; j < 4; j++) pk[j] = (u32)f2bf(v[2 * j]) | ((u32)f2bf(v[2 * j + 1]) << 16);
        *(uint4*)&As[r][kc * 8] = *(uint4*)pk;
        *(uint4*)&Bs[r][kc * 8] = *(const uint4*)&wih[(size_t)(n0 + r) * 512 + k];
        __syncthreads();
        bf16x8 af[2], bfr[2];
#pragma unroll
        for (int mi = 0; mi < 2; mi++) af[mi] = *(const bf16x8*)&As[wr * 32 + mi * 16 + (lane & 15)][(lane >> 4) * 8];
#pragma unroll
        for (int ni = 0; ni < 2; ni++) bfr[ni] = *(const bf16x8*)&Bs[wc * 32 + ni * 16 + (lane & 15)][(lane >> 4) * 8];
#pragma unroll
        for (int mi = 0; mi < 2; mi++)
#pragma unroll
            for (int ni = 0; ni < 2; ni++)
                acc[mi][ni] = __builtin_amdgcn_mfma_f32_16x16x32_bf16(af[mi], bfr[ni], acc[mi][ni], 0, 0, 0);
        __syncthreads();
    }
#pragma unroll
    for (int mi = 0; mi < 2; mi++)
#pragma unroll
        for (int ni = 0; ni < 2; ni++) {
            int row = m0 + wr * 32 + mi * 16 + (lane >> 4) * 4;
            int col = n0 + wc * 32 + ni * 16 + (lane & 15);
            float bias = bih[col];
#pragma unroll
            for (int i = 0; i < 4; i++)
                xp[(size_t)(row + i) * GA + col] = f2bf(acc[mi][ni][i] + bias);
        }
}

// ---------------- serial GRU: 4 WGs/batch on ONE XCD, L2 fast-path exchange ----------------
// blk -> (b, role): b = (blk&7)|((blk>>5)<<3), role=(blk>>3)&3  => XCD(blk%8)=b%8 for all roles
// ring: u32 [b][slot 0..7][slice 0..2][128], word = (f16(h)<<16) | (t+1);  bprog: u32[16]
__global__ __launch_bounds__(512) void k_serial(
        const float* __restrict__ whhA, const float* __restrict__ bhhA,
        const float* __restrict__ wihB, const float* __restrict__ whhB,
        const float* __restrict__ bhhB, const u16* __restrict__ xp,
        const float* __restrict__ cpart, const float* __restrict__ h0a,
        const float* __restrict__ h0b, u32* hEx, u32* bprog,
        float* __restrict__ yB) {
    const int blk = blockIdx.x, tid = threadIdx.x;
    const int b = (blk & 7) | ((blk >> 5) << 3);
    const int role = (blk >> 3) & 3;

    if (role < 3) {
        // ================= A-WG: units 128*role .. +128 =================
        __shared__ __align__(16) u32 hbuf[2][192];  // hA as f16 pairs, parity
        __shared__ float red[384][5];               // [row][kc] padded
        __shared__ u16 xpb[2][384];                 // xp rows for this WG, parity
        __shared__ int lbB, deadf, fastEn;
        const int s = role;
        const int u = tid & 127, kc = tid >> 7;     // matvec role for tid<384
        u32 w[3][64];
        if (tid < 384) {
#pragma unroll
            for (int g = 0; g < 3; g++) {
                const float* wr = whhA + ((size_t)(g * 384 + s * 128 + u)) * 384 + kc * 128;
#pragma unroll
                for (int c = 0; c < 16; c++)
#pragma unroll
                    for (int j = 0; j < 4; j++)
                        w[g][c * 4 + j] = packpair(wr[c * 8 + 2 * j], wr[c * 8 + 2 * j + 1]);
            }
        }
        if (tid < 192) hbuf[0][tid] = packpair(h0a[b * 384 + 2 * tid], h0a[b * 384 + 2 * tid + 1]);
        const int xcol = (tid >> 7) * 384 + s * 128 + (tid & 127);
        float hprA = 0, bh0 = 0, bh1 = 0, bh2 = 0;
        if (tid < 128) {
            hprA = h0a[b * 384 + s * 128 + tid];
            bh0 = bhhA[s * 128 + tid];
            bh1 = bhhA[384 + s * 128 + tid];
            bh2 = bhhA[768 + s * 128 + tid];
        }
        if (tid < 384) xpb[0][tid] = xp[((size_t)b * S_LEN) * GA + xcol];
        if (tid == 0) { lbB = 0; deadf = 0; fastEn = 1; }
        __syncthreads();

        for (int t = 0; t < S_LEN; ++t) {
            const int p = t & 1, p2 = p ^ 1;
            u16 xnext = 0;
            int lbn = -1;
            // PHASE1: pollers fetch peers' h(t-1); matvec threads issue xp(t+1)
            if (tid < 384) {
                if (t + 1 < S_LEN) xnext = xp[((size_t)b * S_LEN + t + 1) * GA + xcol];
                if (tid == 0) lbn = (int)ald32(bprog + b);
            } else if (t > 0) {
                const int i = tid - 384, pi = i >> 6, idx = i & 63;
                const int ps = pi + (pi >= s ? 1 : 0);
                const u64* src = (const u64*)hEx + (((size_t)b * 8 + ((t - 1) & 7)) * 3 + ps) * 64 + idx;
                u64 v = poll64(src, (u32)t & 0xffffu, &fastEn, &deadf);
                hbuf[p][ps * 64 + idx] = (((u32)v) >> 16) | (((u32)(v >> 32)) & 0xffff0000u);
            }
            __syncthreads();  // S1
            // PHASE2: matvec
            if (tid < 384) {
                const uint4* hb4 = (const uint4*)&hbuf[p][0] + kc * 16;
                float a00 = 0, a01 = 0, a10 = 0, a11 = 0, a20 = 0, a21 = 0;
#pragma unroll
                for (int c = 0; c < 16; c++) {
                    uint4 hc = hb4[c];
                    a00 = dot2p(w[0][4 * c + 0], hc.x, a00); a01 = dot2p(w[0][4 * c + 1], hc.y, a01);
                    a00 = dot2p(w[0][4 * c + 2], hc.z, a00); a01 = dot2p(w[0][4 * c + 3], hc.w, a01);
                    a10 = dot2p(w[1][4 * c + 0], hc.x, a10); a11 = dot2p(w[1][4 * c + 1], hc.y, a11);
                    a10 = dot2p(w[1][4 * c + 2], hc.z, a10); a11 = dot2p(w[1][4 * c + 3], hc.w, a11);
                    a20 = dot2p(w[2][4 * c + 0], hc.x, a20); a21 = dot2p(w[2][4 * c + 1], hc.y, a21);
                    a20 = dot2p(w[2][4 * c + 2], hc.z, a20); a21 = dot2p(w[2][4 * c + 3], hc.w, a21);
                }
                red[u][kc] = a00 + a01;
                red[128 + u][kc] = a10 + a11;
                red[256 + u][kc] = a20 + a21;
                if (t + 1 < S_LEN) xpb[p2][tid] = xnext;
                if (tid == 0 && lbn >= 0) lbB = lbn;
            }
            __syncthreads();  // S2
            // PHASE3: gates + publish
            if (tid < 128) {
                if (t - 7 > lbB && !deadf) {
                    int cnt = 0;
                    while ((int)ald32(bprog + b) < t - 7) {
                        if (++cnt > CAPP) { deadf = 1; break; }
                    }
                }
                float pr = red[tid][0] + red[tid][1] + red[tid][2] + bh0;
                float pz = red[128 + tid][0] + red[128 + tid][1] + red[128 + tid][2] + bh1;
                float pn = red[256 + tid][0] + red[256 + tid][1] + red[256 + tid][2] + bh2;
                float rg = sigm(bf2f(xpb[p][tid]) + pr);
                float zg = sigm(bf2f(xpb[p][128 + tid]) + pz);
                float ng = tanh_(bf2f(xpb[p][256 + tid]) + rg * pn);
                float hnew = (1.f - zg) * ng + zg * hprA;
                hprA = hnew;
                u16 hb16 = pack1(hnew);
                ((u16*)&hbuf[p2][0])[s * 128 + tid] = hb16;
                pub32(hEx + (((size_t)b * 8 + (t & 7)) * 3 + s) * 128 + tid,
                      ((u32)hb16 << 16) | (u32)(t + 1));
            }
            // next S1 provides ordering
        }
    } else {
        // ================= B-WG: all 64 GRU-B units, hB fully local =================
        __shared__ __align__(16) u32 hbufA[192];
        __shared__ __align__(16) u16 hbB[2][64];
        __shared__ float redy[192][3];
        __shared__ float redh[192];
        __shared__ float cpl[32][192];
        __shared__ int deadB, fastEnB;
        const int r = (tid < 192) ? tid : tid - 192;
        const int kh = (tid < 192) ? 0 : 1;
        u32 wy[96];
        if (tid < 384) {
            const float* wr = wihB + (size_t)r * 512 + kh * 192;
#pragma unroll
            for (int i = 0; i < 96; i++) wy[i] = packpair(wr[2 * i], wr[2 * i + 1]);
        }
        u32 wb0[32], wb1[32];
        if (tid >= 384 && tid < 480) {
            const int rb = (tid - 384) * 2;
            const float* w0p = whhB + (size_t)rb * 64;
            const float* w1p = whhB + (size_t)(rb + 1) * 64;
#pragma unroll
            for (int i = 0; i < 32; i++) {
                wb0[i] = packpair(w0p[2 * i], w0p[2 * i + 1]);
                wb1[i] = packpair(w1p[2 * i], w1p[2 * i + 1]);
            }
        }
        for (int i = tid; i < 32 * 192; i += 512)
            cpl[i / 192][i % 192] = cpart[((size_t)b * 32) * 192 + i];
        float bB0 = 0, bB1 = 0, bB2 = 0, hprB = 0;
        if (tid < 64) {
            bB0 = bhhB[tid]; bB1 = bhhB[64 + tid]; bB2 = bhhB[128 + tid];
            hprB = h0b[b * 64 + tid];
            hbB[0][tid] = pack1(hprB);
        }
        if (tid == 0) { deadB = 0; fastEnB = 1; }
        __syncthreads();

        for (int tb = 0; tb < S_LEN; ++tb) {
            const int p = tb & 1, p2 = p ^ 1;
            // PHASE1: poll hA(tb)
            if (tid < 192) {
                const int ps = tid >> 6, idx = tid & 63;
                const u64* src = (const u64*)hEx + (((size_t)b * 8 + (tb & 7)) * 3 + ps) * 64 + idx;
                u64 v = poll64(src, (u32)(tb + 1) & 0xffffu, &fastEnB, &deadB);
                hbufA[ps * 64 + idx] = (((u32)v) >> 16) | (((u32)(v >> 32)) & 0xffff0000u);
            }
            __syncthreads();  // S1
            // PHASE2: matvecs
            if (tid < 384) {
                const uint4* hb4 = (const uint4*)&hbufA[0] + kh * 24;
                float a0 = 0, a1 = 0;
#pragma unroll
                for (int c = 0; c < 24; c++) {
                    uint4 hc = hb4[c];
                    a0 = dot2p(wy[4 * c + 0], hc.x, a0); a1 = dot2p(wy[4 * c + 1], hc.y, a1);
                    a0 = dot2p(wy[4 * c + 2], hc.z, a0); a1 = dot2p(wy[4 * c + 3], hc.w, a1);
                }
                redy[r][kh] = a0 + a1;
            } else if (tid < 480) {
                const uint4* hb4 = (const uint4*)&hbB[p][0];
                float a0 = 0, b0 = 0;
#pragma unroll
                for (int q = 0; q < 8; q++) {
                    uint4 hc = hb4[q];
                    a0 = dot2p(wb0[4 * q + 0], hc.x, a0); a0 = dot2p(wb0[4 * q + 1], hc.y, a0);
                    a0 = dot2p(wb0[4 * q + 2], hc.z, a0); a0 = dot2p(wb0[4 * q + 3], hc.w, a0);
                    b0 = dot2p(wb1[4 * q + 0], hc.x, b0); b0 = dot2p(wb1[4 * q + 1], hc.y, b0);
                    b0 = dot2p(wb1[4 * q + 2], hc.z, b0); b0 = dot2p(wb1[4 * q + 3], hc.w, b0);
                }
                const int rb = (tid - 384) * 2;
                redh[rb] = a0;
                redh[rb + 1] = b0;
            }
            __syncthreads();  // S2
            // PHASE3: gates + yB + progress
            if (tid < 64) {
                const int fr = tb / 160;
                float xr = redy[tid][0] + redy[tid][1] + cpl[fr][tid];
                float xz = redy[64 + tid][0] + redy[64 + tid][1] + cpl[fr][64 + tid];
                float xn = redy[128 + tid][0] + redy[128 + tid][1] + cpl[fr][128 + tid];
                float hr = redh[tid] + bB0;
                float hz = redh[64 + tid] + bB1;
                float hn = redh[128 + tid] + bB2;
                float rg = sigm(xr + hr);
                float zg = sigm(xz + hz);
                float ng = tanh_(xn + rg * hn);
                float hnew = (1.f - zg) * ng + zg * hprB;
                hprB = hnew;
                hbB[p2][tid] = pack1(hnew);
                yB[((size_t)b * S_LEN + tb) * UB + tid] = hnew;
                if (tid == 0) ast32(bprog + b, (u32)(tb + 1));
            }
        }
    }
}

// ---------------- dual FC + log_softmax ----------------
__global__ __launch_bounds__(256) void k_fc(const float* __restrict__ yB, const float* __restrict__ w1,
                                            const float* __restrict__ b1, const float* __restrict__ w2,
                                            const float* __restrict__ b2, const float* __restrict__ alpha,
                                            const float* __restrict__ beta, float* __restrict__ out) {
    __shared__ float yb[4][64];
    __shared__ float vb[4][256];
    int tid = threadIdx.x;
    size_t r0 = (size_t)blockIdx.x * 4;
    { int r = tid >> 6, k = tid & 63; yb[r][k] = yB[(r0 + r) * 64 + k]; }
    __syncthreads();
    int o = tid;
    float a1[4] = {0, 0, 0, 0}, a2[4] = {0, 0, 0, 0};
    for (int k = 0; k < 64; k += 4) {
        float4 u = *(const float4*)(w1 + o * 64 + k);
        float4 v = *(const float4*)(w2 + o * 64 + k);
#pragma unroll
        for (int r = 0; r < 4; r++) {
            float y0 = yb[r][k], y1 = yb[r][k + 1], y2 = yb[r][k + 2], y3 = yb[r][k + 3];
            a1[r] = fmaf(u.x, y0, fmaf(u.y, y1, fmaf(u.z, y2, fmaf(u.w, y3, a1[r]))));
            a2[r] = fmaf(v.x, y0, fmaf(v.y, y1, fmaf(v.z, y2, fmaf(v.w, y3, a2[r]))));
        }
    }
    float al = alpha[o], be = beta[o], c1 = b1[o], c2 = b2[o];
#pragma unroll
    for (int r = 0; r < 4; r++)
        vb[r][o] = al * tanh_(a1[r] + c1) + be * tanh_(a2[r] + c2);
    __syncthreads();
    int wv = tid >> 6, l = tid & 63;
    float x0 = vb[wv][l], x1 = vb[wv][64 + l], x2 = vb[wv][128 + l], x3 = vb[wv][192 + l];
    float m = fmaxf(fmaxf(x0, x1), fmaxf(x2, x3));
#pragma unroll
    for (int off = 1; off < 64; off <<= 1) m = fmaxf(m, __shfl_xor(m, off));
    float sum = __expf(x0 - m) + __expf(x1 - m) + __expf(x2 - m) + __expf(x3 - m);
#pragma unroll
    for (int off = 1; off < 64; off <<= 1) sum += __shfl_xor(sum, off);
    float lse = m + __logf(sum);
    float* po = out + (r0 + wv) * 256;
    po[l] = x0 - lse;
    po[64 + l] = x1 - lse;
    po[128 + l] = x2 - lse;
    po[192 + l] = x3 - lse;
}

extern "C" void kernel_launch(void* const* d_in, const int* in_sizes, int n_in,
                              void* d_out, int out_size, void* d_ws, size_t ws_size,
                              hipStream_t stream) {
    const float* features = (const float*)d_in[0];
    const int* periods = (const int*)d_in[1];
    const int* signals = (const int*)d_in[2];
    const float* gruA0 = (const float*)d_in[3];
    const float* gruB0 = (const float*)d_in[4];
    const float* period_emb = (const float*)d_in[5];
    const float* signal_emb = (const float*)d_in[6];
    const float* conv1_w = (const float*)d_in[7];
    const float* conv1_b = (const float*)d_in[8];
    const float* conv2_w = (const float*)d_in[9];
    const float* conv2_b = (const float*)d_in[10];
    const float* fd1_w = (const float*)d_in[11];
    const float* fd1_b = (const float*)d_in[12];
    const float* fd2_w = (const float*)d_in[13];
    const float* fd2_b = (const float*)d_in[14];
    const float* grua_wih = (const float*)d_in[15];
    const float* grua_whh = (const float*)d_in[16];
    const float* grua_bih = (const float*)d_in[17];
    const float* grua_bhh = (const float*)d_in[18];
    const float* grub_wih = (const float*)d_in[19];
    const float* grub_whh = (const float*)d_in[20];
    const float* grub_bih = (const float*)d_in[21];
    const float* grub_bhh = (const float*)d_in[22];
    const float* fc1_w = (const float*)d_in[23];
    const float* fc1_b = (const float*)d_in[24];
    const float* fc2_w = (const float*)d_in[25];
    const float* fc2_b = (const float*)d_in[26];
    const float* alpha = (const float*)d_in[27];
    const float* beta = (const float*)d_in[28];
    float* out = (float*)d_out;

    char* ws = (char*)d_ws;
    size_t off = 0;
    auto alloc = [&](size_t bytes) { void* p = ws + off; off += (bytes + 255) & ~(size_t)255; return p; };
    u16* xp = (u16*)alloc((size_t)16 * 5120 * 1152 * 2);
    u16* wihA = (u16*)alloc((size_t)1152 * 512 * 2);
    float* c1 = (float*)alloc((size_t)16 * 34 * 128 * 4);
    float* c2 = (float*)alloc((size_t)16 * 32 * 128 * 4);
    float* cc = (float*)alloc((size_t)16 * 32 * 128 * 4);
    float* cpart = (float*)alloc((size_t)16 * 32 * 192 * 4);
    float* yB = (float*)alloc((size_t)16 * 5120 * 64 * 4);
    u32* hEx = (u32*)alloc((size_t)49408 * 4);  // ring 16*8*3*128 + bprog(16) + pad
    u32* bprog = hEx + 49152;

    k_cvt<<<dim3(2304), dim3(256), 0, stream>>>(grua_wih, wihA);
    k_frame1<<<dim3(34, 16), dim3(128), 0, stream>>>(features, periods, period_emb, conv1_w, conv1_b, c1);
    k_frame2<<<dim3(32, 16), dim3(128), 0, stream>>>(c1, conv2_w, conv2_b, c2);
    k_fd<<<dim3(32, 16), dim3(128), 0, stream>>>(c2, fd1_w, fd1_b, fd2_w, fd2_b, cc);
    k_cpart<<<dim3(32, 16), dim3(192), 0, stream>>>(cc, grub_wih, grub_bih, cpart);
    k_init<<<dim3(193), dim3(256), 0, stream>>>(hEx);
    k_gemm<<<dim3(1280, 18), dim3(256), 0, stream>>>(signals, signal_emb, cc, wihA, grua_bih, xp);
    k_serial<<<dim3(64), dim3(512), 0, stream>>>(grua_whh, grua_bhh, grub_wih, grub_whh, grub_bhh,
                                                 xp, cpart, gruA0, gruB0, hEx, bprog, yB);
    k_fc<<<dim3(20480), dim3(256), 0, stream>>>(yB, fc1_w, fc1_b, fc2_w, fc2_b, alpha, beta, out);
}

// Round 9
// 10260.640 us; speedup vs baseline: 1.6191x; 1.1884x over previous
//
#include <hip/hip_runtime.h>

typedef unsigned short u16;
typedef unsigned int u32;
typedef unsigned long long u64;
typedef __attribute__((ext_vector_type(8))) short bf16x8;
typedef __attribute__((ext_vector_type(4))) float f32x4;

#define S_LEN 5120
#define UB 64
#define GA 1152
#define CAPP (1 << 16)
#define FASTCAP 3000
#define RING_WORDS (16 * 8 * 3 * 128)

__device__ __forceinline__ float bf2f(u16 u) { return __uint_as_float(((u32)u) << 16); }
__device__ __forceinline__ u16 f2bf(float f) {
    u32 x = __float_as_uint(f);
    return (u16)((x + 0x7fffu + ((x >> 16) & 1u)) >> 16);
}
__device__ __forceinline__ float blo(u32 w) { return __uint_as_float(w << 16); }
__device__ __forceinline__ float bhi(u32 w) { return __uint_as_float(w & 0xffff0000u); }
__device__ __forceinline__ float sigm(float x) { return 1.f / (1.f + __expf(-x)); }
__device__ __forceinline__ float tanh_(float x) { float e = __expf(2.f * x); return 1.f - 2.f / (e + 1.f); }

#if __has_builtin(__builtin_amdgcn_fdot2)
typedef _Float16 h2v __attribute__((ext_vector_type(2)));
__device__ __forceinline__ float dot2p(u32 w, u32 h, float acc) {
    return __builtin_amdgcn_fdot2(__builtin_bit_cast(h2v, w), __builtin_bit_cast(h2v, h), acc, false);
}
__device__ __forceinline__ u32 packpair(float a, float b) {
    u16 x = __builtin_bit_cast(u16, (_Float16)a);
    u16 y = __builtin_bit_cast(u16, (_Float16)b);
    return (u32)x | ((u32)y << 16);
}
__device__ __forceinline__ u16 pack1(float a) { return __builtin_bit_cast(u16, (_Float16)a); }
#else
__device__ __forceinline__ float dot2p(u32 w, u32 h, float acc) {
    acc = fmaf(blo(w), blo(h), acc);
    return fmaf(bhi(w), bhi(h), acc);
}
__device__ __forceinline__ u32 packpair(float a, float b) { return (u32)f2bf(a) | ((u32)f2bf(b) << 16); }
__device__ __forceinline__ u16 pack1(float a) { return f2bf(a); }
#endif

__device__ __forceinline__ u64 ald64(const u64* p) {
    return __hip_atomic_load(p, __ATOMIC_RELAXED, __HIP_MEMORY_SCOPE_AGENT);
}
__device__ __forceinline__ u32 ald32(const u32* p) {
    return __hip_atomic_load(p, __ATOMIC_RELAXED, __HIP_MEMORY_SCOPE_AGENT);
}
__device__ __forceinline__ void ast32(u32* p, u32 v) {
    __hip_atomic_store(p, v, __ATOMIC_RELAXED, __HIP_MEMORY_SCOPE_AGENT);
}
// L1-bypassing load/store: same-XCD exchange through the shared (write-back) L2
__device__ __forceinline__ u64 ld64_sc0(const u64* p) {
    u64 v;
    asm volatile("global_load_dwordx2 %0, %1, off sc0\n\ts_waitcnt vmcnt(0)"
                 : "=v"(v) : "v"(p) : "memory");
    return v;
}
__device__ __forceinline__ void st32_sc0(u32* p, u32 v) {
    asm volatile("global_store_dword %0, %1, off sc0" :: "v"(p), "v"(v) : "memory");
}
// publish: fast (L2-resident) address + slow (agent-coherent) address — DIFFERENT lines
__device__ __forceinline__ void pub32(u32* fastp, u32* slowp, u32 v) {
    st32_sc0(fastp, v);
    ast32(slowp, v);
}
__device__ __forceinline__ u64 poll64(const u64* fastp, const u64* slowp, u32 tg,
                                      bool allowFast, int* fastEn, int* dead) {
    u64 v;
    if (allowFast && *fastEn) {
        for (int i = 0; i < FASTCAP; ++i) {
            v = ld64_sc0(fastp);
            if (((u32)v & 0xffffu) == tg && (((u32)(v >> 32)) & 0xffffu) == tg) return v;
        }
        *fastEn = 0;  // placement assumption failed: degrade this WG permanently
    }
    int cnt = 0;
    for (;;) {
        v = ald64(slowp);
        if (((u32)v & 0xffffu) == tg && (((u32)(v >> 32)) & 0xffffu) == tg) return v;
        if (*dead || ++cnt > CAPP) { *dead = 1; return v; }
    }
}

// ---------------- convert grua_wih to bf16 ----------------
__global__ __launch_bounds__(256) void k_cvt(const float* __restrict__ src, u16* __restrict__ dst) {
    int i = blockIdx.x * 256 + threadIdx.x;
    dst[i] = f2bf(src[i]);
}

// ---------------- frame-rate network ----------------
__global__ __launch_bounds__(128) void k_frame1(const float* __restrict__ features, const int* __restrict__ periods,
                                                const float* __restrict__ pemb, const float* __restrict__ w,
                                                const float* __restrict__ bias, float* __restrict__ c1) {
    __shared__ float fin[3][84];
    int t = blockIdx.x, b = blockIdx.y, o = threadIdx.x;
    for (int i = threadIdx.x; i < 252; i += 128) {
        int kk = i / 84, ci = i % 84, tt = t + kk;
        float v;
        if (ci < 20) v = features[(b * 36 + tt) * 20 + ci];
        else v = pemb[periods[b * 36 + tt] * 64 + (ci - 20)];
        fin[kk][ci] = v;
    }
    __syncthreads();
    float acc = bias[o];
    for (int kk = 0; kk < 3; kk++)
        for (int ci = 0; ci < 84; ci++)
            acc = fmaf(fin[kk][ci], w[o * 252 + ci * 3 + kk], acc);
    c1[(b * 34 + t) * 128 + o] = tanh_(acc);
}

__global__ __launch_bounds__(128) void k_frame2(const float* __restrict__ c1, const float* __restrict__ w,
                                                const float* __restrict__ bias, float* __restrict__ c2) {
    __shared__ float fin[3][128];
    int t = blockIdx.x, b = blockIdx.y, o = threadIdx.x;
    for (int i = threadIdx.x; i < 384; i += 128) {
        int kk = i >> 7, ci = i & 127;
        fin[kk][ci] = c1[(b * 34 + t + kk) * 128 + ci];
    }
    __syncthreads();
    float acc = bias[o];
    for (int kk = 0; kk < 3; kk++)
        for (int ci = 0; ci < 128; ci++)
            acc = fmaf(fin[kk][ci], w[o * 384 + ci * 3 + kk], acc);
    c2[(b * 32 + t) * 128 + o] = tanh_(acc);
}

__global__ __launch_bounds__(128) void k_fd(const float* __restrict__ c2, const float* __restrict__ w1,
                                            const float* __restrict__ b1, const float* __restrict__ w2,
                                            const float* __restrict__ b2, float* __restrict__ cc) {
    __shared__ float a0[128], a1s[128];
    int t = blockIdx.x, b = blockIdx.y, o = threadIdx.x;
    a0[o] = c2[(b * 32 + t) * 128 + o];
    __syncthreads();
    float acc = b1[o];
    for (int k = 0; k < 128; k++) acc = fmaf(a0[k], w1[o * 128 + k], acc);
    a1s[o] = tanh_(acc);
    __syncthreads();
    float acc2 = b2[o];
    for (int k = 0; k < 128; k++) acc2 = fmaf(a1s[k], w2[o * 128 + k], acc2);
    cc[(b * 32 + t) * 128 + o] = tanh_(acc2);
}

// cpart[b][fr][192] = grub_wih[:,384:512] @ c[b][fr] + grub_bih
__global__ __launch_bounds__(192) void k_cpart(const float* __restrict__ cc, const float* __restrict__ wihB,
                                               const float* __restrict__ bihB, float* __restrict__ cpart) {
    __shared__ float cl[128];
    int fr = blockIdx.x, b = blockIdx.y, o = threadIdx.x;
    if (o < 128) cl[o] = cc[(b * 32 + fr) * 128 + o];
    __syncthreads();
    float acc = bihB[o];
    for (int k = 0; k < 128; k++) acc = fmaf(cl[k], wihB[o * 512 + 384 + k], acc);
    cpart[((size_t)b * 32 + fr) * 192 + o] = acc;
}

// ---------------- init: clear BOTH rings + bprog with agent-scope stores ----------------
__global__ __launch_bounds__(256) void k_init(u32* base, int n) {
    int i = blockIdx.x * 256 + threadIdx.x;
    if (i < n) ast32(base + i, 0u);
}

// ---------------- GRU-A input projection GEMM ----------------
__global__ __launch_bounds__(256) void k_gemm(const int* __restrict__ signals, const float* __restrict__ semb,
                                              const float* __restrict__ c, const u16* __restrict__ wih,
                                              const float* __restrict__ bih, u16* __restrict__ xp) {
    __shared__ u16 As[64][40];
    __shared__ u16 Bs[64][40];
    int m0 = blockIdx.x * 64, n0 = blockIdx.y * 64;
    int tid = threadIdx.x;
    int r = tid >> 2, kc = tid & 3;
    int lane = tid & 63, wv = tid >> 6;
    int wr = wv >> 1, wc = wv & 1;
    int mrow = m0 + r;
    int b = mrow / S_LEN, s = mrow % S_LEN;
    const int* sigrow = signals + mrow * 3;
    const float* crow = c + ((size_t)(b * 32) + s / 160) * 128;
    f32x4 acc[2][2];
#pragma unroll
    for (int i = 0; i < 2; i++)
#pragma unroll
        for (int j = 0; j < 2; j++) { acc[i][j][0] = 0.f; acc[i][j][1] = 0.f; acc[i][j][2] = 0.f; acc[i][j][3] = 0.f; }
    for (int k0 = 0; k0 < 512; k0 += 32) {
        int k = k0 + kc * 8;
        float v[8];
        if (k < 384) {
            int idx = sigrow[k >> 7];
            const float* src = semb + idx * 128 + (k & 127);
#pragma unroll
            for (int j = 0; j < 8; j++) v[j] = src[j];
        } else {
            const float* src = crow + (k - 384);
#pragma unroll
            for (int j = 0; j < 8; j++) v[j] = src[j];
        }
        u32 pk[4];
#pragma unroll
        for (int j = 0; j < 4; j++) pk[j] = (u32)f2bf(v[2 * j]) | ((u32)f2bf(v[2 * j + 1]) << 16);
        *(uint4*)&As[r][kc * 8] = *(uint4*)pk;
        *(uint4*)&Bs[r][kc * 8] = *(const uint4*)&wih[(size_t)(n0 + r) * 512 + k];
        __syncthreads();
        bf16x8 af[2], bfr[2];
#pragma unroll
        for (int mi = 0; mi < 2; mi++) af[mi] = *(const bf16x8*)&As[wr * 32 + mi * 16 + (lane & 15)][(lane >> 4) * 8];
#pragma unroll
        for (int ni = 0; ni < 2; ni++) bfr[ni] = *(const bf16x8*)&Bs[wc * 32 + ni * 16 + (lane & 15)][(lane >> 4) * 8];
#pragma unroll
        for (int mi = 0; mi < 2; mi++)
#pragma unroll
            for (int ni = 0; ni < 2; ni++)
                acc[mi][ni] = __builtin_amdgcn_mfma_f32_16x16x32_bf16(af[mi], bfr[ni], acc[mi][ni], 0, 0, 0);
        __syncthreads();
    }
#pragma unroll
    for (int mi = 0; mi < 2; mi++)
#pragma unroll
        for (int ni = 0; ni < 2; ni++) {
            int row = m0 + wr * 32 + mi * 16 + (lane >> 4) * 4;
            int col = n0 + wc * 32 + ni * 16 + (lane & 15);
            float bias = bih[col];
#pragma unroll
            for (int i = 0; i < 4; i++)
                xp[(size_t)(row + i) * GA + col] = f2bf(acc[mi][ni][i] + bias);
        }
}

// ---------------- serial GRU: 4 WGs/batch on ONE XCD, dual-ring (L2 fast + L3 slow) ----------------
// blk -> (b, role): b = (blk&7)|((blk>>5)<<3), role=(blk>>3)&3  => XCD(blk%8)=b%8 for all roles
// ring layout (both rings): u32 [b][slot 0..7][slice 0..2][128], word = (f16(h)<<16) | (t+1)
__global__ __launch_bounds__(512) void k_serial(
        const float* __restrict__ whhA, const float* __restrict__ bhhA,
        const float* __restrict__ wihB, const float* __restrict__ whhB,
        const float* __restrict__ bhhB, const u16* __restrict__ xp,
        const float* __restrict__ cpart, const float* __restrict__ h0a,
        const float* __restrict__ h0b, u32* hExF, u32* hExS, u32* bprog,
        float* __restrict__ yB) {
    const int blk = blockIdx.x, tid = threadIdx.x;
    const int b = (blk & 7) | ((blk >> 5) << 3);
    const int role = (blk >> 3) & 3;

    if (role < 3) {
        // ================= A-WG: units 128*role .. +128 =================
        __shared__ __align__(16) u32 hbuf[2][192];  // hA as f16 pairs, parity
        __shared__ float red[384][5];               // [row][kc] padded
        __shared__ u16 xpb[2][384];                 // xp rows for this WG, parity
        __shared__ int lbB, deadf, fastEn;
        const int s = role;
        const int u = tid & 127, kc = tid >> 7;     // matvec role for tid<384
        u32 w[3][64];
        if (tid < 384) {
#pragma unroll
            for (int g = 0; g < 3; g++) {
                const float* wr = whhA + ((size_t)(g * 384 + s * 128 + u)) * 384 + kc * 128;
#pragma unroll
                for (int c = 0; c < 16; c++)
#pragma unroll
                    for (int j = 0; j < 4; j++)
                        w[g][c * 4 + j] = packpair(wr[c * 8 + 2 * j], wr[c * 8 + 2 * j + 1]);
            }
        }
        if (tid < 192) hbuf[0][tid] = packpair(h0a[b * 384 + 2 * tid], h0a[b * 384 + 2 * tid + 1]);
        const int xcol = (tid >> 7) * 384 + s * 128 + (tid & 127);
        float hprA = 0, bh0 = 0, bh1 = 0, bh2 = 0;
        if (tid < 128) {
            hprA = h0a[b * 384 + s * 128 + tid];
            bh0 = bhhA[s * 128 + tid];
            bh1 = bhhA[384 + s * 128 + tid];
            bh2 = bhhA[768 + s * 128 + tid];
        }
        if (tid < 384) xpb[0][tid] = xp[((size_t)b * S_LEN) * GA + xcol];
        if (tid == 0) { lbB = 0; deadf = 0; fastEn = 1; }
        __syncthreads();

        for (int t = 0; t < S_LEN; ++t) {
            const int p = t & 1, p2 = p ^ 1;
            u16 xnext = 0;
            int lbn = -1;
            // PHASE1: pollers fetch peers' h(t-1); matvec threads issue xp(t+1)
            if (tid < 384) {
                if (t + 1 < S_LEN) xnext = xp[((size_t)b * S_LEN + t + 1) * GA + xcol];
                if (tid == 0) lbn = (int)ald32(bprog + b);
            } else if (t > 0) {
                const int i = tid - 384, pi = i >> 6, idx = i & 63;
                const int ps = pi + (pi >= s ? 1 : 0);
                const size_t woff = (((size_t)b * 8 + ((t - 1) & 7)) * 3 + ps) * 64 + idx;
                u64 v = poll64((const u64*)hExF + woff, (const u64*)hExS + woff,
                               (u32)t & 0xffffu, t >= 2, &fastEn, &deadf);
                hbuf[p][ps * 64 + idx] = (((u32)v) >> 16) | (((u32)(v >> 32)) & 0xffff0000u);
            }
            __syncthreads();  // S1
            // PHASE2: matvec
            if (tid < 384) {
                const uint4* hb4 = (const uint4*)&hbuf[p][0] + kc * 16;
                float a00 = 0, a01 = 0, a10 = 0, a11 = 0, a20 = 0, a21 = 0;
#pragma unroll
                for (int c = 0; c < 16; c++) {
                    uint4 hc = hb4[c];
                    a00 = dot2p(w[0][4 * c + 0], hc.x, a00); a01 = dot2p(w[0][4 * c + 1], hc.y, a01);
                    a00 = dot2p(w[0][4 * c + 2], hc.z, a00); a01 = dot2p(w[0][4 * c + 3], hc.w, a01);
                    a10 = dot2p(w[1][4 * c + 0], hc.x, a10); a11 = dot2p(w[1][4 * c + 1], hc.y, a11);
                    a10 = dot2p(w[1][4 * c + 2], hc.z, a10); a11 = dot2p(w[1][4 * c + 3], hc.w, a11);
                    a20 = dot2p(w[2][4 * c + 0], hc.x, a20); a21 = dot2p(w[2][4 * c + 1], hc.y, a21);
                    a20 = dot2p(w[2][4 * c + 2], hc.z, a20); a21 = dot2p(w[2][4 * c + 3], hc.w, a21);
                }
                red[u][kc] = a00 + a01;
                red[128 + u][kc] = a10 + a11;
                red[256 + u][kc] = a20 + a21;
                if (t + 1 < S_LEN) xpb[p2][tid] = xnext;
                if (tid == 0 && lbn >= 0) lbB = lbn;
            }
            __syncthreads();  // S2
            // PHASE3: gates + publish
            if (tid < 128) {
                if (t - 7 > lbB && !deadf) {
                    int cnt = 0;
                    while ((int)ald32(bprog + b) < t - 7) {
                        if (++cnt > CAPP) { deadf = 1; break; }
                    }
                }
                float pr = red[tid][0] + red[tid][1] + red[tid][2] + bh0;
                float pz = red[128 + tid][0] + red[128 + tid][1] + red[128 + tid][2] + bh1;
                float pn = red[256 + tid][0] + red[256 + tid][1] + red[256 + tid][2] + bh2;
                float rg = sigm(bf2f(xpb[p][tid]) + pr);
                float zg = sigm(bf2f(xpb[p][128 + tid]) + pz);
                float ng = tanh_(bf2f(xpb[p][256 + tid]) + rg * pn);
                float hnew = (1.f - zg) * ng + zg * hprA;
                hprA = hnew;
                u16 hb16 = pack1(hnew);
                ((u16*)&hbuf[p2][0])[s * 128 + tid] = hb16;
                const size_t poff = (((size_t)b * 8 + (t & 7)) * 3 + s) * 128 + tid;
                pub32(hExF + poff, hExS + poff, ((u32)hb16 << 16) | (u32)(t + 1));
            }
            // next S1 provides ordering
        }
    } else {
        // ================= B-WG: all 64 GRU-B units, hB fully local =================
        __shared__ __align__(16) u32 hbufA[192];
        __shared__ __align__(16) u16 hbB[2][64];
        __shared__ float redy[192][3];
        __shared__ float redh[192];
        __shared__ float cpl[32][192];
        __shared__ int deadB, fastEnB;
        const int r = (tid < 192) ? tid : tid - 192;
        const int kh = (tid < 192) ? 0 : 1;
        u32 wy[96];
        if (tid < 384) {
            const float* wr = wihB + (size_t)r * 512 + kh * 192;
#pragma unroll
            for (int i = 0; i < 96; i++) wy[i] = packpair(wr[2 * i], wr[2 * i + 1]);
        }
        u32 wb0[32], wb1[32];
        if (tid >= 384 && tid < 480) {
            const int rb = (tid - 384) * 2;
            const float* w0p = whhB + (size_t)rb * 64;
            const float* w1p = whhB + (size_t)(rb + 1) * 64;
#pragma unroll
            for (int i = 0; i < 32; i++) {
                wb0[i] = packpair(w0p[2 * i], w0p[2 * i + 1]);
                wb1[i] = packpair(w1p[2 * i], w1p[2 * i + 1]);
            }
        }
        for (int i = tid; i < 32 * 192; i += 512)
            cpl[i / 192][i % 192] = cpart[((size_t)b * 32) * 192 + i];
        float bB0 = 0, bB1 = 0, bB2 = 0, hprB = 0;
        if (tid < 64) {
            bB0 = bhhB[tid]; bB1 = bhhB[64 + tid]; bB2 = bhhB[128 + tid];
            hprB = h0b[b * 64 + tid];
            hbB[0][tid] = pack1(hprB);
        }
        if (tid == 0) { deadB = 0; fastEnB = 1; }
        __syncthreads();

        for (int tb = 0; tb < S_LEN; ++tb) {
            const int p = tb & 1, p2 = p ^ 1;
            // PHASE1: poll hA(tb)
            if (tid < 192) {
                const int ps = tid >> 6, idx = tid & 63;
                const size_t woff = (((size_t)b * 8 + (tb & 7)) * 3 + ps) * 64 + idx;
                u64 v = poll64((const u64*)hExF + woff, (const u64*)hExS + woff,
                               (u32)(tb + 1) & 0xffffu, tb >= 1, &fastEnB, &deadB);
                hbufA[ps * 64 + idx] = (((u32)v) >> 16) | (((u32)(v >> 32)) & 0xffff0000u);
            }
            __syncthreads();  // S1
            // PHASE2: matvecs
            if (tid < 384) {
                const uint4* hb4 = (const uint4*)&hbufA[0] + kh * 24;
                float a0 = 0, a1 = 0;
#pragma unroll
                for (int c = 0; c < 24; c++) {
                    uint4 hc = hb4[c];
                    a0 = dot2p(wy[4 * c + 0], hc.x, a0); a1 = dot2p(wy[4 * c + 1], hc.y, a1);
                    a0 = dot2p(wy[4 * c + 2], hc.z, a0); a1 = dot2p(wy[4 * c + 3], hc.w, a1);
                }
                redy[r][kh] = a0 + a1;
            } else if (tid < 480) {
                const uint4* hb4 = (const uint4*)&hbB[p][0];
                float a0 = 0, b0 = 0;
#pragma unroll
                for (int q = 0; q < 8; q++) {
                    uint4 hc = hb4[q];
                    a0 = dot2p(wb0[4 * q + 0], hc.x, a0); a0 = dot2p(wb0[4 * q + 1], hc.y, a0);
                    a0 = dot2p(wb0[4 * q + 2], hc.z, a0); a0 = dot2p(wb0[4 * q + 3], hc.w, a0);
                    b0 = dot2p(wb1[4 * q + 0], hc.x, b0); b0 = dot2p(wb1[4 * q + 1], hc.y, b0);
                    b0 = dot2p(wb1[4 * q + 2], hc.z, b0); b0 = dot2p(wb1[4 * q + 3], hc.w, b0);
                }
                const int rb = (tid - 384) * 2;
                redh[rb] = a0;
                redh[rb + 1] = b0;
            }
            __syncthreads();  // S2
            // PHASE3: gates + yB + progress
            if (tid < 64) {
                const int fr = tb / 160;
                float xr = redy[tid][0] + redy[tid][1] + cpl[fr][tid];
                float xz = redy[64 + tid][0] + redy[64 + tid][1] + cpl[fr][64 + tid];
                float xn = redy[128 + tid][0] + redy[128 + tid][1] + cpl[fr][128 + tid];
                float hr = redh[tid] + bB0;
                float hz = redh[64 + tid] + bB1;
                float hn = redh[128 + tid] + bB2;
                float rg = sigm(xr + hr);
                float zg = sigm(xz + hz);
                float ng = tanh_(xn + rg * hn);
                float hnew = (1.f - zg) * ng + zg * hprB;
                hprB = hnew;
                hbB[p2][tid] = pack1(hnew);
                yB[((size_t)b * S_LEN + tb) * UB + tid] = hnew;
                if (tid == 0) ast32(bprog + b, (u32)(tb + 1));
            }
        }
    }
}

// ---------------- dual FC + log_softmax ----------------
__global__ __launch_bounds__(256) void k_fc(const float* __restrict__ yB, const float* __restrict__ w1,
                                            const float* __restrict__ b1, const float* __restrict__ w2,
                                            const float* __restrict__ b2, const float* __restrict__ alpha,
                                            const float* __restrict__ beta, float* __restrict__ out) {
    __shared__ float yb[4][64];
    __shared__ float vb[4][256];
    int tid = threadIdx.x;
    size_t r0 = (size_t)blockIdx.x * 4;
    { int r = tid >> 6, k = tid & 63; yb[r][k] = yB[(r0 + r) * 64 + k]; }
    __syncthreads();
    int o = tid;
    float a1[4] = {0, 0, 0, 0}, a2[4] = {0, 0, 0, 0};
    for (int k = 0; k < 64; k += 4) {
        float4 u = *(const float4*)(w1 + o * 64 + k);
        float4 v = *(const float4*)(w2 + o * 64 + k);
#pragma unroll
        for (int r = 0; r < 4; r++) {
            float y0 = yb[r][k], y1 = yb[r][k + 1], y2 = yb[r][k + 2], y3 = yb[r][k + 3];
            a1[r] = fmaf(u.x, y0, fmaf(u.y, y1, fmaf(u.z, y2, fmaf(u.w, y3, a1[r]))));
            a2[r] = fmaf(v.x, y0, fmaf(v.y, y1, fmaf(v.z, y2, fmaf(v.w, y3, a2[r]))));
        }
    }
    float al = alpha[o], be = beta[o], c1 = b1[o], c2 = b2[o];
#pragma unroll
    for (int r = 0; r < 4; r++)
        vb[r][o] = al * tanh_(a1[r] + c1) + be * tanh_(a2[r] + c2);
    __syncthreads();
    int wv = tid >> 6, l = tid & 63;
    float x0 = vb[wv][l], x1 = vb[wv][64 + l], x2 = vb[wv][128 + l], x3 = vb[wv][192 + l];
    float m = fmaxf(fmaxf(x0, x1), fmaxf(x2, x3));
#pragma unroll
    for (int off = 1; off < 64; off <<= 1) m = fmaxf(m, __shfl_xor(m, off));
    float sum = __expf(x0 - m) + __expf(x1 - m) + __expf(x2 - m) + __expf(x3 - m);
#pragma unroll
    for (int off = 1; off < 64; off <<= 1) sum += __shfl_xor(sum, off);
    float lse = m + __logf(sum);
    float* po = out + (r0 + wv) * 256;
    po[l] = x0 - lse;
    po[64 + l] = x1 - lse;
    po[128 + l] = x2 - lse;
    po[192 + l] = x3 - lse;
}

extern "C" void kernel_launch(void* const* d_in, const int* in_sizes, int n_in,
                              void* d_out, int out_size, void* d_ws, size_t ws_size,
                              hipStream_t stream) {
    const float* features = (const float*)d_in[0];
    const int* periods = (const int*)d_in[1];
    const int* signals = (const int*)d_in[2];
    const float* gruA0 = (const float*)d_in[3];
    const float* gruB0 = (const float*)d_in[4];
    const float* period_emb = (const float*)d_in[5];
    const float* signal_emb = (const float*)d_in[6];
    const float* conv1_w = (const float*)d_in[7];
    const float* conv1_b = (const float*)d_in[8];
    const float* conv2_w = (const float*)d_in[9];
    const float* conv2_b = (const float*)d_in[10];
    const float* fd1_w = (const float*)d_in[11];
    const float* fd1_b = (const float*)d_in[12];
    const float* fd2_w = (const float*)d_in[13];
    const float* fd2_b = (const float*)d_in[14];
    const float* grua_wih = (const float*)d_in[15];
    const float* grua_whh = (const float*)d_in[16];
    const float* grua_bih = (const float*)d_in[17];
    const float* grua_bhh = (const float*)d_in[18];
    const float* grub_wih = (const float*)d_in[19];
    const float* grub_whh = (const float*)d_in[20];
    const float* grub_bih = (const float*)d_in[21];
    const float* grub_bhh = (const float*)d_in[22];
    const float* fc1_w = (const float*)d_in[23];
    const float* fc1_b = (const float*)d_in[24];
    const float* fc2_w = (const float*)d_in[25];
    const float* fc2_b = (const float*)d_in[26];
    const float* alpha = (const float*)d_in[27];
    const float* beta = (const float*)d_in[28];
    float* out = (float*)d_out;

    char* ws = (char*)d_ws;
    size_t off = 0;
    auto alloc = [&](size_t bytes) { void* p = ws + off; off += (bytes + 255) & ~(size_t)255; return p; };
    u16* xp = (u16*)alloc((size_t)16 * 5120 * 1152 * 2);
    u16* wihA = (u16*)alloc((size_t)1152 * 512 * 2);
    float* c1 = (float*)alloc((size_t)16 * 34 * 128 * 4);
    float* c2 = (float*)alloc((size_t)16 * 32 * 128 * 4);
    float* cc = (float*)alloc((size_t)16 * 32 * 128 * 4);
    float* cpart = (float*)alloc((size_t)16 * 32 * 192 * 4);
    float* yB = (float*)alloc((size_t)16 * 5120 * 64 * 4);
    u32* hExF = (u32*)alloc((size_t)RING_WORDS * 4);          // fast ring (L2-resident, sc0)
    u32* hExS = (u32*)alloc((size_t)(RING_WORDS + 256) * 4);  // slow ring (agent) + bprog
    u32* bprog = hExS + RING_WORDS;
    const int initN = 2 * RING_WORDS + 256;

    k_cvt<<<dim3(2304), dim3(256), 0, stream>>>(grua_wih, wihA);
    k_frame1<<<dim3(34, 16), dim3(128), 0, stream>>>(features, periods, period_emb, conv1_w, conv1_b, c1);
    k_frame2<<<dim3(32, 16), dim3(128), 0, stream>>>(c1, conv2_w, conv2_b, c2);
    k_fd<<<dim3(32, 16), dim3(128), 0, stream>>>(c2, fd1_w, fd1_b, fd2_w, fd2_b, cc);
    k_cpart<<<dim3(32, 16), dim3(192), 0, stream>>>(cc, grub_wih, grub_bih, cpart);
    k_init<<<dim3((initN + 255) / 256), dim3(256), 0, stream>>>(hExF, initN);
    k_gemm<<<dim3(1280, 18), dim3(256), 0, stream>>>(signals, signal_emb, cc, wihA, grua_bih, xp);
    k_serial<<<dim3(64), dim3(512), 0, stream>>>(grua_whh, grua_bhh, grub_wih, grub_whh, grub_bhh,
                                                 xp, cpart, gruA0, gruB0, hExF, hExS, bprog, yB);
    k_fc<<<dim3(20480), dim3(256), 0, stream>>>(yB, fc1_w, fc1_b, fc2_w, fc2_b, alpha, beta, out);
}

// Round 11
// 10195.995 us; speedup vs baseline: 1.6294x; 1.0063x over previous
//
#include <hip/hip_runtime.h>

typedef unsigned short u16;
typedef unsigned int u32;
typedef unsigned long long u64;
typedef __attribute__((ext_vector_type(8))) short bf16x8;
typedef __attribute__((ext_vector_type(4))) float f32x4;

#define S_LEN 5120
#define UB 64
#define GA 1152
#define CAPP (1 << 16)
#define FASTCAP 3000
#define RING_WORDS (16 * 8 * 3 * 128)

__device__ __forceinline__ float bf2f(u16 u) { return __uint_as_float(((u32)u) << 16); }
__device__ __forceinline__ u16 f2bf(float f) {
    u32 x = __float_as_uint(f);
    return (u16)((x + 0x7fffu + ((x >> 16) & 1u)) >> 16);
}
__device__ __forceinline__ float blo(u32 w) { return __uint_as_float(w << 16); }
__device__ __forceinline__ float bhi(u32 w) { return __uint_as_float(w & 0xffff0000u); }
__device__ __forceinline__ float sigm(float x) { return 1.f / (1.f + __expf(-x)); }
__device__ __forceinline__ float tanh_(float x) { float e = __expf(2.f * x); return 1.f - 2.f / (e + 1.f); }

#if __has_builtin(__builtin_amdgcn_fdot2)
typedef _Float16 h2v __attribute__((ext_vector_type(2)));
__device__ __forceinline__ float dot2p(u32 w, u32 h, float acc) {
    return __builtin_amdgcn_fdot2(__builtin_bit_cast(h2v, w), __builtin_bit_cast(h2v, h), acc, false);
}
__device__ __forceinline__ u32 packpair(float a, float b) {
    u16 x = __builtin_bit_cast(u16, (_Float16)a);
    u16 y = __builtin_bit_cast(u16, (_Float16)b);
    return (u32)x | ((u32)y << 16);
}
__device__ __forceinline__ u16 pack1(float a) { return __builtin_bit_cast(u16, (_Float16)a); }
#else
__device__ __forceinline__ float dot2p(u32 w, u32 h, float acc) {
    acc = fmaf(blo(w), blo(h), acc);
    return fmaf(bhi(w), bhi(h), acc);
}
__device__ __forceinline__ u32 packpair(float a, float b) { return (u32)f2bf(a) | ((u32)f2bf(b) << 16); }
__device__ __forceinline__ u16 pack1(float a) { return f2bf(a); }
#endif

__device__ __forceinline__ u64 ald64(const u64* p) {
    return __hip_atomic_load(p, __ATOMIC_RELAXED, __HIP_MEMORY_SCOPE_AGENT);
}
__device__ __forceinline__ u32 ald32(const u32* p) {
    return __hip_atomic_load(p, __ATOMIC_RELAXED, __HIP_MEMORY_SCOPE_AGENT);
}
__device__ __forceinline__ void ast32(u32* p, u32 v) {
    __hip_atomic_store(p, v, __ATOMIC_RELAXED, __HIP_MEMORY_SCOPE_AGENT);
}
// L1-bypassing load/store: same-XCD exchange through the shared L2
__device__ __forceinline__ u64 ld64_sc0(const u64* p) {
    u64 v;
    asm volatile("global_load_dwordx2 %0, %1, off sc0\n\ts_waitcnt vmcnt(0)"
                 : "=v"(v) : "v"(p) : "memory");
    return v;
}
__device__ __forceinline__ void st32_sc0(u32* p, u32 v) {
    asm volatile("global_store_dword %0, %1, off sc0" :: "v"(p), "v"(v) : "memory");
}
__device__ __forceinline__ void pub32(u32* fastp, u32* slowp, u32 v) {
    st32_sc0(fastp, v);
    ast32(slowp, v);   // floats: no barrier drain forces its ack
}
__device__ __forceinline__ u64 poll64(const u64* fastp, const u64* slowp, u32 tg,
                                      bool allowFast, int* fastEn, int* dead) {
    u64 v;
    if (allowFast && *fastEn) {
        for (int i = 0; i < FASTCAP; ++i) {
            v = ld64_sc0(fastp);
            if (((u32)v & 0xffffu) == tg && (((u32)(v >> 32)) & 0xffffu) == tg) return v;
        }
        *fastEn = 0;
    }
    int cnt = 0;
    for (;;) {
        v = ald64(slowp);
        if (((u32)v & 0xffffu) == tg && (((u32)(v >> 32)) & 0xffffu) == tg) return v;
        if (*dead || ++cnt > CAPP) { *dead = 1; return v; }
    }
}
// Raw WG barrier: drain ONLY LDS; global stores/loads float across (self-tagged protocol
// needs no global ordering at barriers; intra-WG data passes exclusively through LDS).
__device__ __forceinline__ void wgbar() {
    __builtin_amdgcn_sched_barrier(0);
    asm volatile("s_waitcnt lgkmcnt(0)" ::: "memory");
    __builtin_amdgcn_s_barrier();
    __builtin_amdgcn_sched_barrier(0);
}

// ---------------- convert grua_wih to bf16 ----------------
__global__ __launch_bounds__(256) void k_cvt(const float* __restrict__ src, u16* __restrict__ dst) {
    int i = blockIdx.x * 256 + threadIdx.x;
    dst[i] = f2bf(src[i]);
}

// ---------------- frame-rate network ----------------
__global__ __launch_bounds__(128) void k_frame1(const float* __restrict__ features, const int* __restrict__ periods,
                                                const float* __restrict__ pemb, const float* __restrict__ w,
                                                const float* __restrict__ bias, float* __restrict__ c1) {
    __shared__ float fin[3][84];
    int t = blockIdx.x, b = blockIdx.y, o = threadIdx.x;
    for (int i = threadIdx.x; i < 252; i += 128) {
        int kk = i / 84, ci = i % 84, tt = t + kk;
        float v;
        if (ci < 20) v = features[(b * 36 + tt) * 20 + ci];
        else v = pemb[periods[b * 36 + tt] * 64 + (ci - 20)];
        fin[kk][ci] = v;
    }
    __syncthreads();
    float acc = bias[o];
    for (int kk = 0; kk < 3; kk++)
        for (int ci = 0; ci < 84; ci++)
            acc = fmaf(fin[kk][ci], w[o * 252 + ci * 3 + kk], acc);
    c1[(b * 34 + t) * 128 + o] = tanh_(acc);
}

__global__ __launch_bounds__(128) void k_frame2(const float* __restrict__ c1, const float* __restrict__ w,
                                                const float* __restrict__ bias, float* __restrict__ c2) {
    __shared__ float fin[3][128];
    int t = blockIdx.x, b = blockIdx.y, o = threadIdx.x;
    for (int i = threadIdx.x; i < 384; i += 128) {
        int kk = i >> 7, ci = i & 127;
        fin[kk][ci] = c1[(b * 34 + t + kk) * 128 + ci];
    }
    __syncthreads();
    float acc = bias[o];
    for (int kk = 0; kk < 3; kk++)
        for (int ci = 0; ci < 128; ci++)
            acc = fmaf(fin[kk][ci], w[o * 384 + ci * 3 + kk], acc);
    c2[(b * 32 + t) * 128 + o] = tanh_(acc);
}

__global__ __launch_bounds__(128) void k_fd(const float* __restrict__ c2, const float* __restrict__ w1,
                                            const float* __restrict__ b1, const float* __restrict__ w2,
                                            const float* __restrict__ b2, float* __restrict__ cc) {
    __shared__ float a0[128], a1s[128];
    int t = blockIdx.x, b = blockIdx.y, o = threadIdx.x;
    a0[o] = c2[(b * 32 + t) * 128 + o];
    __syncthreads();
    float acc = b1[o];
    for (int k = 0; k < 128; k++) acc = fmaf(a0[k], w1[o * 128 + k], acc);
    a1s[o] = tanh_(acc);
    __syncthreads();
    float acc2 = b2[o];
    for (int k = 0; k < 128; k++) acc2 = fmaf(a1s[k], w2[o * 128 + k], acc2);
    cc[(b * 32 + t) * 128 + o] = tanh_(acc2);
}

// cpart[b][fr][192] = grub_wih[:,384:512] @ c[b][fr] + grub_bih
__global__ __launch_bounds__(192) void k_cpart(const float* __restrict__ cc, const float* __restrict__ wihB,
                                               const float* __restrict__ bihB, float* __restrict__ cpart) {
    __shared__ float cl[128];
    int fr = blockIdx.x, b = blockIdx.y, o = threadIdx.x;
    if (o < 128) cl[o] = cc[(b * 32 + fr) * 128 + o];
    __syncthreads();
    float acc = bihB[o];
    for (int k = 0; k < 128; k++) acc = fmaf(cl[k], wihB[o * 512 + 384 + k], acc);
    cpart[((size_t)b * 32 + fr) * 192 + o] = acc;
}

// ---------------- init: clear BOTH rings + bprog with agent-scope stores ----------------
__global__ __launch_bounds__(256) void k_init(u32* base, int n) {
    int i = blockIdx.x * 256 + threadIdx.x;
    if (i < n) ast32(base + i, 0u);
}

// ---------------- GRU-A input projection GEMM ----------------
__global__ __launch_bounds__(256) void k_gemm(const int* __restrict__ signals, const float* __restrict__ semb,
                                              const float* __restrict__ c, const u16* __restrict__ wih,
                                              const float* __restrict__ bih, u16* __restrict__ xp) {
    __shared__ u16 As[64][40];
    __shared__ u16 Bs[64][40];
    int m0 = blockIdx.x * 64, n0 = blockIdx.y * 64;
    int tid = threadIdx.x;
    int r = tid >> 2, kc = tid & 3;
    int lane = tid & 63, wv = tid >> 6;
    int wr = wv >> 1, wc = wv & 1;
    int mrow = m0 + r;
    int b = mrow / S_LEN, s = mrow % S_LEN;
    const int* sigrow = signals + mrow * 3;
    const float* crow = c + ((size_t)(b * 32) + s / 160) * 128;
    f32x4 acc[2][2];
#pragma unroll
    for (int i = 0; i < 2; i++)
#pragma unroll
        for (int j = 0; j < 2; j++) { acc[i][j][0] = 0.f; acc[i][j][1] = 0.f; acc[i][j][2] = 0.f; acc[i][j][3] = 0.f; }
    for (int k0 = 0; k0 < 512; k0 += 32) {
        int k = k0 + kc * 8;
        float v[8];
        if (k < 384) {
            int idx = sigrow[k >> 7];
            const float* src = semb + idx * 128 + (k & 127);
#pragma unroll
            for (int j = 0; j < 8; j++) v[j] = src[j];
        } else {
            const float* src = crow + (k - 384);
#pragma unroll
            for (int j = 0; j < 8; j++) v[j] = src[j];
        }
        u32 pk[4];
#pragma unroll
        for (int j = 0; j < 4; j++) pk[j] = (u32)f2bf(v[2 * j]) | ((u32)f2bf(v[2 * j + 1]) << 16);
        *(uint4*)&As[r][kc * 8] = *(uint4*)pk;
        *(uint4*)&Bs[r][kc * 8] = *(const uint4*)&wih[(size_t)(n0 + r) * 512 + k];
        __syncthreads();
        bf16x8 af[2], bfr[2];
#pragma unroll
        for (int mi = 0; mi < 2; mi++) af[mi] = *(const bf16x8*)&As[wr * 32 + mi * 16 + (lane & 15)][(lane >> 4) * 8];
#pragma unroll
        for (int ni = 0; ni < 2; ni++) bfr[ni] = *(const bf16x8*)&Bs[wc * 32 + ni * 16 + (lane & 15)][(lane >> 4) * 8];
#pragma unroll
        for (int mi = 0; mi < 2; mi++)
#pragma unroll
            for (int ni = 0; ni < 2; ni++)
                acc[mi][ni] = __builtin_amdgcn_mfma_f32_16x16x32_bf16(af[mi], bfr[ni], acc[mi][ni], 0, 0, 0);
        __syncthreads();
    }
#pragma unroll
    for (int mi = 0; mi < 2; mi++)
#pragma unroll
        for (int ni = 0; ni < 2; ni++) {
            int row = m0 + wr * 32 + mi * 16 + (lane >> 4) * 4;
            int col = n0 + wc * 32 + ni * 16 + (lane & 15);
            float bias = bih[col];
#pragma unroll
            for (int i = 0; i < 4; i++)
                xp[(size_t)(row + i) * GA + col] = f2bf(acc[mi][ni][i] + bias);
        }
}

// ---------------- serial GRU: 4 WGs/batch on ONE XCD, L2 exchange, float-store barriers ----------------
// blk -> (b, role): b = (blk&7)|((blk>>5)<<3), role=(blk>>3)&3  => XCD(blk%8)=b%8 for all roles
// A-WG roles: gates 0-127 (NO loads); matvec 0-383; xp loaders 128-383 (slots j1=tid-128 and,
// for tid<256, j2=tid+128); pollers 384-511 (polls only).
// xp slot j in [0,384) holds column (j>>7)*384 + s*128 + (j&127).
__global__ __launch_bounds__(512) void k_serial(
        const float* __restrict__ whhA, const float* __restrict__ bhhA,
        const float* __restrict__ wihB, const float* __restrict__ whhB,
        const float* __restrict__ bhhB, const u16* __restrict__ xp,
        const float* __restrict__ cpart, const float* __restrict__ h0a,
        const float* __restrict__ h0b, u32* hExF, u32* hExS, u32* bprog,
        float* __restrict__ yB) {
    const int blk = blockIdx.x, tid = threadIdx.x;
    const int b = (blk & 7) | ((blk >> 5) << 3);
    const int role = (blk >> 3) & 3;

    if (role < 3) {
        // ================= A-WG: units 128*role .. +128 =================
        __shared__ __align__(16) u32 hbuf[2][192];
        __shared__ float red[384][5];
        __shared__ u16 xpb[2][384];
        __shared__ int lbB, deadf, fastEn;
        const int s = role;
        const int u = tid & 127, kc = tid >> 7;
        u32 w[3][64];
        if (tid < 384) {
#pragma unroll
            for (int g = 0; g < 3; g++) {
                const float* wr = whhA + ((size_t)(g * 384 + s * 128 + u)) * 384 + kc * 128;
#pragma unroll
                for (int c = 0; c < 16; c++)
#pragma unroll
                    for (int j = 0; j < 4; j++)
                        w[g][c * 4 + j] = packpair(wr[c * 8 + 2 * j], wr[c * 8 + 2 * j + 1]);
            }
        }
        if (tid < 192) hbuf[0][tid] = packpair(h0a[b * 384 + 2 * tid], h0a[b * 384 + 2 * tid + 1]);
        // xp slots: j1 = tid-128 (slots 0..255), j2 = tid+128 (slots 256..383, only tid<256)
        const int j1 = tid - 128;
        const int xcol1 = (tid >= 128 && tid < 512) ? ((j1 >> 7) * 384 + s * 128 + (j1 & 127)) : 0;
        const int j2 = tid + 128;
        const int xcol2 = (tid >= 128 && tid < 256) ? ((j2 >> 7) * 384 + s * 128 + (j2 & 127)) : 0;
        float hprA = 0, bh0 = 0, bh1 = 0, bh2 = 0;
        if (tid < 128) {
            hprA = h0a[b * 384 + s * 128 + tid];
            bh0 = bhhA[s * 128 + tid];
            bh1 = bhhA[384 + s * 128 + tid];
            bh2 = bhhA[768 + s * 128 + tid];
        }
        if (tid >= 128 && tid < 384) xpb[0][j1] = xp[((size_t)b * S_LEN) * GA + xcol1];
        if (tid >= 128 && tid < 256) xpb[0][j2] = xp[((size_t)b * S_LEN) * GA + xcol2];
        if (tid == 0) { lbB = 0; deadf = 0; fastEn = 1; }
        __syncthreads();

        for (int t = 0; t < S_LEN; ++t) {
            const int p = t & 1, p2 = p ^ 1;
            const bool hasx = (t + 1 < S_LEN);
            u16 xq1 = 0, xq2 = 0;
            int lbn = -1;
            // PHASE1
            if (tid >= 384) {
                if (t > 0) {
                    const int i = tid - 384, pi = i >> 6, idx = i & 63;
                    const int ps = pi + (pi >= s ? 1 : 0);
                    const size_t woff = (((size_t)b * 8 + ((t - 1) & 7)) * 3 + ps) * 64 + idx;
                    u64 v = poll64((const u64*)hExF + woff, (const u64*)hExS + woff,
                                   (u32)t & 0xffffu, t >= 2, &fastEn, &deadf);
                    hbuf[p][ps * 64 + idx] = (((u32)v) >> 16) | (((u32)(v >> 32)) & 0xffff0000u);
                }
            } else if (tid >= 128) {
                if (hasx) {
                    xq1 = xp[((size_t)b * S_LEN + t + 1) * GA + xcol1];
                    if (tid < 256) xq2 = xp[((size_t)b * S_LEN + t + 1) * GA + xcol2];
                }
                if (tid == 383 && (t & 3) == 0) lbn = (int)ald32(bprog + b);
            }
            wgbar();  // S1 (LDS-only drain)
            // PHASE2: matvec
            if (tid < 384) {
                const uint4* hb4 = (const uint4*)&hbuf[p][0] + kc * 16;
                float a00 = 0, a01 = 0, a10 = 0, a11 = 0, a20 = 0, a21 = 0;
#pragma unroll
                for (int c = 0; c < 16; c++) {
                    uint4 hc = hb4[c];
                    a00 = dot2p(w[0][4 * c + 0], hc.x, a00); a01 = dot2p(w[0][4 * c + 1], hc.y, a01);
                    a00 = dot2p(w[0][4 * c + 2], hc.z, a00); a01 = dot2p(w[0][4 * c + 3], hc.w, a01);
                    a10 = dot2p(w[1][4 * c + 0], hc.x, a10); a11 = dot2p(w[1][4 * c + 1], hc.y, a11);
                    a10 = dot2p(w[1][4 * c + 2], hc.z, a10); a11 = dot2p(w[1][4 * c + 3], hc.w, a11);
                    a20 = dot2p(w[2][4 * c + 0], hc.x, a20); a21 = dot2p(w[2][4 * c + 1], hc.y, a21);
                    a20 = dot2p(w[2][4 * c + 2], hc.z, a20); a21 = dot2p(w[2][4 * c + 3], hc.w, a21);
                }
                red[u][kc] = a00 + a01;
                red[128 + u][kc] = a10 + a11;
                red[256 + u][kc] = a20 + a21;
            }
            if (hasx && tid >= 128 && tid < 384) {
                xpb[p2][j1] = xq1;
                if (tid < 256) xpb[p2][j2] = xq2;
            }
            if (tid == 383 && lbn >= 0) lbB = lbn;
            wgbar();  // S2
            // PHASE3: gates + publish (gate threads have NO loads -> their stores float)
            if (tid < 128) {
                float pr = red[tid][0] + red[tid][1] + red[tid][2] + bh0;
                float pz = red[128 + tid][0] + red[128 + tid][1] + red[128 + tid][2] + bh1;
                float pn = red[256 + tid][0] + red[256 + tid][1] + red[256 + tid][2] + bh2;
                float rg = sigm(bf2f(xpb[p][tid]) + pr);
                float zg = sigm(bf2f(xpb[p][128 + tid]) + pz);
                float ng = tanh_(bf2f(xpb[p][256 + tid]) + rg * pn);
                float hnew = (1.f - zg) * ng + zg * hprA;
                hprA = hnew;
                u16 hb16 = pack1(hnew);
                ((u16*)&hbuf[p2][0])[s * 128 + tid] = hb16;
                if (t - 7 > lbB && !deadf) {
                    int cnt = 0;
                    while ((int)ald32(bprog + b) < t - 7) {
                        if (++cnt > CAPP) { deadf = 1; break; }
                    }
                }
                const size_t poff = (((size_t)b * 8 + (t & 7)) * 3 + s) * 128 + tid;
                pub32(hExF + poff, hExS + poff, ((u32)hb16 << 16) | (u32)(t + 1));
            }
        }
    } else {
        // ================= B-WG: all 64 GRU-B units, hB fully local =================
        __shared__ __align__(16) u32 hbufA[192];
        __shared__ __align__(16) u16 hbB[2][64];
        __shared__ float redy[192][3];
        __shared__ float redh[192];
        __shared__ float cpl[32][192];
        __shared__ int deadB, fastEnB;
        const int r = (tid < 192) ? tid : tid - 192;
        const int kh = (tid < 192) ? 0 : 1;
        u32 wy[96];
        if (tid < 384) {
            const float* wr = wihB + (size_t)r * 512 + kh * 192;
#pragma unroll
            for (int i = 0; i < 96; i++) wy[i] = packpair(wr[2 * i], wr[2 * i + 1]);
        }
        u32 wb0[32], wb1[32];
        if (tid >= 384 && tid < 480) {
            const int rb = (tid - 384) * 2;
            const float* w0p = whhB + (size_t)rb * 64;
            const float* w1p = whhB + (size_t)(rb + 1) * 64;
#pragma unroll
            for (int i = 0; i < 32; i++) {
                wb0[i] = packpair(w0p[2 * i], w0p[2 * i + 1]);
                wb1[i] = packpair(w1p[2 * i], w1p[2 * i + 1]);
            }
        }
        for (int i = tid; i < 32 * 192; i += 512)
            cpl[i / 192][i % 192] = cpart[((size_t)b * 32) * 192 + i];
        float bB0 = 0, bB1 = 0, bB2 = 0, hprB = 0;
        if (tid < 64) {
            bB0 = bhhB[tid]; bB1 = bhhB[64 + tid]; bB2 = bhhB[128 + tid];
            hprB = h0b[b * 64 + tid];
            hbB[0][tid] = pack1(hprB);
        }
        if (tid == 0) { deadB = 0; fastEnB = 1; }
        __syncthreads();

        for (int tb = 0; tb < S_LEN; ++tb) {
            const int p = tb & 1, p2 = p ^ 1;
            // PHASE1: pollers are tid 192-383 (kh=1 redy threads; they issue NO stores)
            if (tid >= 192 && tid < 384) {
                const int i = tid - 192, ps = i >> 6, idx = i & 63;
                const size_t woff = (((size_t)b * 8 + (tb & 7)) * 3 + ps) * 64 + idx;
                u64 v = poll64((const u64*)hExF + woff, (const u64*)hExS + woff,
                               (u32)(tb + 1) & 0xffffu, tb >= 1, &fastEnB, &deadB);
                hbufA[ps * 64 + idx] = (((u32)v) >> 16) | (((u32)(v >> 32)) & 0xffff0000u);
            }
            wgbar();  // S1
            // PHASE2: matvecs
            if (tid < 384) {
                const uint4* hb4 = (const uint4*)&hbufA[0] + kh * 24;
                float a0 = 0, a1 = 0;
#pragma unroll
                for (int c = 0; c < 24; c++) {
                    uint4 hc = hb4[c];
                    a0 = dot2p(wy[4 * c + 0], hc.x, a0); a1 = dot2p(wy[4 * c + 1], hc.y, a1);
                    a0 = dot2p(wy[4 * c + 2], hc.z, a0); a1 = dot2p(wy[4 * c + 3], hc.w, a1);
                }
                redy[r][kh] = a0 + a1;
            } else if (tid < 480) {
                const uint4* hb4 = (const uint4*)&hbB[p][0];
                float a0 = 0, b0 = 0;
#pragma unroll
                for (int q = 0; q < 8; q++) {
                    uint4 hc = hb4[q];
                    a0 = dot2p(wb0[4 * q + 0], hc.x, a0); a0 = dot2p(wb0[4 * q + 1], hc.y, a0);
                    a0 = dot2p(wb0[4 * q + 2], hc.z, a0); a0 = dot2p(wb0[4 * q + 3], hc.w, a0);
                    b0 = dot2p(wb1[4 * q + 0], hc.x, b0); b0 = dot2p(wb1[4 * q + 1], hc.y, b0);
                    b0 = dot2p(wb1[4 * q + 2], hc.z, b0); b0 = dot2p(wb1[4 * q + 3], hc.w, b0);
                }
                const int rb = (tid - 384) * 2;
                redh[rb] = a0;
                redh[rb + 1] = b0;
            }
            wgbar();  // S2
            // PHASE3: gates + yB + progress (tid<64: loads none -> stores float)
            if (tid < 64) {
                const int fr = tb / 160;
                float xr = redy[tid][0] + redy[tid][1] + cpl[fr][tid];
                float xz = redy[64 + tid][0] + redy[64 + tid][1] + cpl[fr][64 + tid];
                float xn = redy[128 + tid][0] + redy[128 + tid][1] + cpl[fr][128 + tid];
                float hr = redh[tid] + bB0;
                float hz = redh[64 + tid] + bB1;
                float hn = redh[128 + tid] + bB2;
                float rg = sigm(xr + hr);
                float zg = sigm(xz + hz);
                float ng = tanh_(xn + rg * hn);
                float hnew = (1.f - zg) * ng + zg * hprB;
                hprB = hnew;
                hbB[p2][tid] = pack1(hnew);
                yB[((size_t)b * S_LEN + tb) * UB + tid] = hnew;
                if (tid == 0) ast32(bprog + b, (u32)(tb + 1));
            }
        }
    }
}

// ---------------- dual FC + log_softmax ----------------
__global__ __launch_bounds__(256) void k_fc(const float* __restrict__ yB, const float* __restrict__ w1,
                                            const float* __restrict__ b1, const float* __restrict__ w2,
                                            const float* __restrict__ b2, const float* __restrict__ alpha,
                                            const float* __restrict__ beta, float* __restrict__ out) {
    __shared__ float yb[4][64];
    __shared__ float vb[4][256];
    int tid = threadIdx.x;
    size_t r0 = (size_t)blockIdx.x * 4;
    { int r = tid >> 6, k = tid & 63; yb[r][k] = yB[(r0 + r) * 64 + k]; }
    __syncthreads();
    int o = tid;
    float a1[4] = {0, 0, 0, 0}, a2[4] = {0, 0, 0, 0};
    for (int k = 0; k < 64; k += 4) {
        float4 u = *(const float4*)(w1 + o * 64 + k);
        float4 v = *(const float4*)(w2 + o * 64 + k);
#pragma unroll
        for (int r = 0; r < 4; r++) {
            float y0 = yb[r][k], y1 = yb[r][k + 1], y2 = yb[r][k + 2], y3 = yb[r][k + 3];
            a1[r] = fmaf(u.x, y0, fmaf(u.y, y1, fmaf(u.z, y2, fmaf(u.w, y3, a1[r]))));
            a2[r] = fmaf(v.x, y0, fmaf(v.y, y1, fmaf(v.z, y2, fmaf(v.w, y3, a2[r]))));
        }
    }
    float al = alpha[o], be = beta[o], c1 = b1[o], c2 = b2[o];
#pragma unroll
    for (int r = 0; r < 4; r++)
        vb[r][o] = al * tanh_(a1[r] + c1) + be * tanh_(a2[r] + c2);
    __syncthreads();
    int wv = tid >> 6, l = tid & 63;
    float x0 = vb[wv][l], x1 = vb[wv][64 + l], x2 = vb[wv][128 + l], x3 = vb[wv][192 + l];
    float m = fmaxf(fmaxf(x0, x1), fmaxf(x2, x3));
#pragma unroll
    for (int off = 1; off < 64; off <<= 1) m = fmaxf(m, __shfl_xor(m, off));
    float sum = __expf(x0 - m) + __expf(x1 - m) + __expf(x2 - m) + __expf(x3 - m);
#pragma unroll
    for (int off = 1; off < 64; off <<= 1) sum += __shfl_xor(sum, off);
    float lse = m + __logf(sum);
    float* po = out + (r0 + wv) * 256;
    po[l] = x0 - lse;
    po[64 + l] = x1 - lse;
    po[128 + l] = x2 - lse;
    po[192 + l] = x3 - lse;
}

extern "C" void kernel_launch(void* const* d_in, const int* in_sizes, int n_in,
                              void* d_out, int out_size, void* d_ws, size_t ws_size,
                              hipStream_t stream) {
    const float* features = (const float*)d_in[0];
    const int* periods = (const int*)d_in[1];
    const int* signals = (const int*)d_in[2];
    const float* gruA0 = (const float*)d_in[3];
    const float* gruB0 = (const float*)d_in[4];
    const float* period_emb = (const float*)d_in[5];
    const float* signal_emb = (const float*)d_in[6];
    const float* conv1_w = (const float*)d_in[7];
    const float* conv1_b = (const float*)d_in[8];
    const float* conv2_w = (const float*)d_in[9];
    const float* conv2_b = (const float*)d_in[10];
    const float* fd1_w = (const float*)d_in[11];
    const float* fd1_b = (const float*)d_in[12];
    const float* fd2_w = (const float*)d_in[13];
    const float* fd2_b = (const float*)d_in[14];
    const float* grua_wih = (const float*)d_in[15];
    const float* grua_whh = (const float*)d_in[16];
    const float* grua_bih = (const float*)d_in[17];
    const float* grua_bhh = (const float*)d_in[18];
    const float* grub_wih = (const float*)d_in[19];
    const float* grub_whh = (const float*)d_in[20];
    const float* grub_bih = (const float*)d_in[21];
    const float* grub_bhh = (const float*)d_in[22];
    const float* fc1_w = (const float*)d_in[23];
    const float* fc1_b = (const float*)d_in[24];
    const float* fc2_w = (const float*)d_in[25];
    const float* fc2_b = (const float*)d_in[26];
    const float* alpha = (const float*)d_in[27];
    const float* beta = (const float*)d_in[28];
    float* out = (float*)d_out;

    char* ws = (char*)d_ws;
    size_t off = 0;
    auto alloc = [&](size_t bytes) { void* p = ws + off; off += (bytes + 255) & ~(size_t)255; return p; };
    u16* xp = (u16*)alloc((size_t)16 * 5120 * 1152 * 2);
    u16* wihA = (u16*)alloc((size_t)1152 * 512 * 2);
    float* c1 = (float*)alloc((size_t)16 * 34 * 128 * 4);
    float* c2 = (float*)alloc((size_t)16 * 32 * 128 * 4);
    float* cc = (float*)alloc((size_t)16 * 32 * 128 * 4);
    float* cpart = (float*)alloc((size_t)16 * 32 * 192 * 4);
    float* yB = (float*)alloc((size_t)16 * 5120 * 64 * 4);
    u32* hExF = (u32*)alloc((size_t)RING_WORDS * 4);          // fast ring (L2-resident, sc0)
    u32* hExS = (u32*)alloc((size_t)(RING_WORDS + 256) * 4);  // slow ring (agent) + bprog
    u32* bprog = hExS + RING_WORDS;
    const int initN = 2 * RING_WORDS + 256;

    k_cvt<<<dim3(2304), dim3(256), 0, stream>>>(grua_wih, wihA);
    k_frame1<<<dim3(34, 16), dim3(128), 0, stream>>>(features, periods, period_emb, conv1_w, conv1_b, c1);
    k_frame2<<<dim3(32, 16), dim3(128), 0, stream>>>(c1, conv2_w, conv2_b, c2);
    k_fd<<<dim3(32, 16), dim3(128), 0, stream>>>(c2, fd1_w, fd1_b, fd2_w, fd2_b, cc);
    k_cpart<<<dim3(32, 16), dim3(192), 0, stream>>>(cc, grub_wih, grub_bih, cpart);
    k_init<<<dim3((initN + 255) / 256), dim3(256), 0, stream>>>(hExF, initN);
    k_gemm<<<dim3(1280, 18), dim3(256), 0, stream>>>(signals, signal_emb, cc, wihA, grua_bih, xp);
    k_serial<<<dim3(64), dim3(512), 0, stream>>>(grua_whh, grua_bhh, grub_wih, grub_whh, grub_bhh,
                                                 xp, cpart, gruA0, gruB0, hExF, hExS, bprog, yB);
    k_fc<<<dim3(20480), dim3(256), 0, stream>>>(yB, fc1_w, fc1_b, fc2_w, fc2_b, alpha, beta, out);
}

// Round 12
// 8762.217 us; speedup vs baseline: 1.8960x; 1.1636x over previous
//
#include <hip/hip_runtime.h>

typedef unsigned short u16;
typedef unsigned int u32;
typedef unsigned long long u64;
typedef __attribute__((ext_vector_type(8))) short bf16x8;
typedef __attribute__((ext_vector_type(4))) float f32x4;

#define S_LEN 5120
#define UB 64
#define GA 1152
#define CAPP (1 << 16)
#define FASTCAP 3000
#define RING_WORDS (16 * 8 * 6 * 64)

__device__ __forceinline__ float bf2f(u16 u) { return __uint_as_float(((u32)u) << 16); }
__device__ __forceinline__ u16 f2bf(float f) {
    u32 x = __float_as_uint(f);
    return (u16)((x + 0x7fffu + ((x >> 16) & 1u)) >> 16);
}
__device__ __forceinline__ float blo(u32 w) { return __uint_as_float(w << 16); }
__device__ __forceinline__ float bhi(u32 w) { return __uint_as_float(w & 0xffff0000u); }
__device__ __forceinline__ float sigm(float x) { return 1.f / (1.f + __expf(-x)); }
__device__ __forceinline__ float tanh_(float x) { float e = __expf(2.f * x); return 1.f - 2.f / (e + 1.f); }

#if __has_builtin(__builtin_amdgcn_fdot2)
typedef _Float16 h2v __attribute__((ext_vector_type(2)));
__device__ __forceinline__ float dot2p(u32 w, u32 h, float acc) {
    return __builtin_amdgcn_fdot2(__builtin_bit_cast(h2v, w), __builtin_bit_cast(h2v, h), acc, false);
}
__device__ __forceinline__ u32 packpair(float a, float b) {
    u16 x = __builtin_bit_cast(u16, (_Float16)a);
    u16 y = __builtin_bit_cast(u16, (_Float16)b);
    return (u32)x | ((u32)y << 16);
}
__device__ __forceinline__ u16 pack1(float a) { return __builtin_bit_cast(u16, (_Float16)a); }
#else
__device__ __forceinline__ float dot2p(u32 w, u32 h, float acc) {
    acc = fmaf(blo(w), blo(h), acc);
    return fmaf(bhi(w), bhi(h), acc);
}
__device__ __forceinline__ u32 packpair(float a, float b) { return (u32)f2bf(a) | ((u32)f2bf(b) << 16); }
__device__ __forceinline__ u16 pack1(float a) { return f2bf(a); }
#endif

__device__ __forceinline__ u64 ald64(const u64* p) {
    return __hip_atomic_load(p, __ATOMIC_RELAXED, __HIP_MEMORY_SCOPE_AGENT);
}
__device__ __forceinline__ u32 ald32(const u32* p) {
    return __hip_atomic_load(p, __ATOMIC_RELAXED, __HIP_MEMORY_SCOPE_AGENT);
}
__device__ __forceinline__ void ast32(u32* p, u32 v) {
    __hip_atomic_store(p, v, __ATOMIC_RELAXED, __HIP_MEMORY_SCOPE_AGENT);
}
// L1-bypassing load/store: same-XCD exchange through the shared L2
__device__ __forceinline__ u64 ld64_sc0(const u64* p) {
    u64 v;
    asm volatile("global_load_dwordx2 %0, %1, off sc0\n\ts_waitcnt vmcnt(0)"
                 : "=v"(v) : "v"(p) : "memory");
    return v;
}
__device__ __forceinline__ void st32_sc0(u32* p, u32 v) {
    asm volatile("global_store_dword %0, %1, off sc0" :: "v"(p), "v"(v) : "memory");
}
__device__ __forceinline__ void pub32(u32* fastp, u32* slowp, u32 v) {
    st32_sc0(fastp, v);
    ast32(slowp, v);   // mirror for cross-XCD fallback; floats (no barrier drain)
}
__device__ __forceinline__ u64 poll64(const u64* fastp, const u64* slowp, u32 tg,
                                      bool allowFast, int* fastEn, int* dead) {
    u64 v;
    if (allowFast && *fastEn) {
        for (int i = 0; i < FASTCAP; ++i) {
            v = ld64_sc0(fastp);
            if (((u32)v & 0xffffu) == tg && (((u32)(v >> 32)) & 0xffffu) == tg) return v;
        }
        *fastEn = 0;
    }
    int cnt = 0;
    for (;;) {
        v = ald64(slowp);
        if (((u32)v & 0xffffu) == tg && (((u32)(v >> 32)) & 0xffffu) == tg) return v;
        if (*dead || ++cnt > CAPP) { *dead = 1; return v; }
    }
}
// Raw WG barrier: drain ONLY LDS; global stores/loads float across.
__device__ __forceinline__ void wgbar() {
    __builtin_amdgcn_sched_barrier(0);
    asm volatile("s_waitcnt lgkmcnt(0)" ::: "memory");
    __builtin_amdgcn_s_barrier();
    __builtin_amdgcn_sched_barrier(0);
}

// ---------------- convert grua_wih to bf16 ----------------
__global__ __launch_bounds__(256) void k_cvt(const float* __restrict__ src, u16* __restrict__ dst) {
    int i = blockIdx.x * 256 + threadIdx.x;
    dst[i] = f2bf(src[i]);
}

// ---------------- frame-rate network ----------------
__global__ __launch_bounds__(128) void k_frame1(const float* __restrict__ features, const int* __restrict__ periods,
                                                const float* __restrict__ pemb, const float* __restrict__ w,
                                                const float* __restrict__ bias, float* __restrict__ c1) {
    __shared__ float fin[3][84];
    int t = blockIdx.x, b = blockIdx.y, o = threadIdx.x;
    for (int i = threadIdx.x; i < 252; i += 128) {
        int kk = i / 84, ci = i % 84, tt = t + kk;
        float v;
        if (ci < 20) v = features[(b * 36 + tt) * 20 + ci];
        else v = pemb[periods[b * 36 + tt] * 64 + (ci - 20)];
        fin[kk][ci] = v;
    }
    __syncthreads();
    float acc = bias[o];
    for (int kk = 0; kk < 3; kk++)
        for (int ci = 0; ci < 84; ci++)
            acc = fmaf(fin[kk][ci], w[o * 252 + ci * 3 + kk], acc);
    c1[(b * 34 + t) * 128 + o] = tanh_(acc);
}

__global__ __launch_bounds__(128) void k_frame2(const float* __restrict__ c1, const float* __restrict__ w,
                                                const float* __restrict__ bias, float* __restrict__ c2) {
    __shared__ float fin[3][128];
    int t = blockIdx.x, b = blockIdx.y, o = threadIdx.x;
    for (int i = threadIdx.x; i < 384; i += 128) {
        int kk = i >> 7, ci = i & 127;
        fin[kk][ci] = c1[(b * 34 + t + kk) * 128 + ci];
    }
    __syncthreads();
    float acc = bias[o];
    for (int kk = 0; kk < 3; kk++)
        for (int ci = 0; ci < 128; ci++)
            acc = fmaf(fin[kk][ci], w[o * 384 + ci * 3 + kk], acc);
    c2[(b * 32 + t) * 128 + o] = tanh_(acc);
}

__global__ __launch_bounds__(128) void k_fd(const float* __restrict__ c2, const float* __restrict__ w1,
                                            const float* __restrict__ b1, const float* __restrict__ w2,
                                            const float* __restrict__ b2, float* __restrict__ cc) {
    __shared__ float a0[128], a1s[128];
    int t = blockIdx.x, b = blockIdx.y, o = threadIdx.x;
    a0[o] = c2[(b * 32 + t) * 128 + o];
    __syncthreads();
    float acc = b1[o];
    for (int k = 0; k < 128; k++) acc = fmaf(a0[k], w1[o * 128 + k], acc);
    a1s[o] = tanh_(acc);
    __syncthreads();
    float acc2 = b2[o];
    for (int k = 0; k < 128; k++) acc2 = fmaf(a1s[k], w2[o * 128 + k], acc2);
    cc[(b * 32 + t) * 128 + o] = tanh_(acc2);
}

// cpart[b][fr][192] = grub_wih[:,384:512] @ c[b][fr] + grub_bih
__global__ __launch_bounds__(192) void k_cpart(const float* __restrict__ cc, const float* __restrict__ wihB,
                                               const float* __restrict__ bihB, float* __restrict__ cpart) {
    __shared__ float cl[128];
    int fr = blockIdx.x, b = blockIdx.y, o = threadIdx.x;
    if (o < 128) cl[o] = cc[(b * 32 + fr) * 128 + o];
    __syncthreads();
    float acc = bihB[o];
    for (int k = 0; k < 128; k++) acc = fmaf(cl[k], wihB[o * 512 + 384 + k], acc);
    cpart[((size_t)b * 32 + fr) * 192 + o] = acc;
}

// ---------------- init: clear BOTH rings + bprog with agent-scope stores ----------------
__global__ __launch_bounds__(256) void k_init(u32* base, int n) {
    int i = blockIdx.x * 256 + threadIdx.x;
    if (i < n) ast32(base + i, 0u);
}

// ---------------- GRU-A input projection GEMM ----------------
__global__ __launch_bounds__(256) void k_gemm(const int* __restrict__ signals, const float* __restrict__ semb,
                                              const float* __restrict__ c, const u16* __restrict__ wih,
                                              const float* __restrict__ bih, u16* __restrict__ xp) {
    __shared__ u16 As[64][40];
    __shared__ u16 Bs[64][40];
    int m0 = blockIdx.x * 64, n0 = blockIdx.y * 64;
    int tid = threadIdx.x;
    int r = tid >> 2, kc = tid & 3;
    int lane = tid & 63, wv = tid >> 6;
    int wr = wv >> 1, wc = wv & 1;
    int mrow = m0 + r;
    int b = mrow / S_LEN, s = mrow % S_LEN;
    const int* sigrow = signals + mrow * 3;
    const float* crow = c + ((size_t)(b * 32) + s / 160) * 128;
    f32x4 acc[2][2];
#pragma unroll
    for (int i = 0; i < 2; i++)
#pragma unroll
        for (int j = 0; j < 2; j++) { acc[i][j][0] = 0.f; acc[i][j][1] = 0.f; acc[i][j][2] = 0.f; acc[i][j][3] = 0.f; }
    for (int k0 = 0; k0 < 512; k0 += 32) {
        int k = k0 + kc * 8;
        float v[8];
        if (k < 384) {
            int idx = sigrow[k >> 7];
            const float* src = semb + idx * 128 + (k & 127);
#pragma unroll
            for (int j = 0; j < 8; j++) v[j] = src[j];
        } else {
            const float* src = crow + (k - 384);
#pragma unroll
            for (int j = 0; j < 8; j++) v[j] = src[j];
        }
        u32 pk[4];
#pragma unroll
        for (int j = 0; j < 4; j++) pk[j] = (u32)f2bf(v[2 * j]) | ((u32)f2bf(v[2 * j + 1]) << 16);
        *(uint4*)&As[r][kc * 8] = *(uint4*)pk;
        *(uint4*)&Bs[r][kc * 8] = *(const uint4*)&wih[(size_t)(n0 + r) * 512 + k];
        __syncthreads();
        bf16x8 af[2], bfr[2];
#pragma unroll
        for (int mi = 0; mi < 2; mi++) af[mi] = *(const bf16x8*)&As[wr * 32 + mi * 16 + (lane & 15)][(lane >> 4) * 8];
#pragma unroll
        for (int ni = 0; ni < 2; ni++) bfr[ni] = *(const bf16x8*)&Bs[wc * 32 + ni * 16 + (lane & 15)][(lane >> 4) * 8];
#pragma unroll
        for (int mi = 0; mi < 2; mi++)
#pragma unroll
            for (int ni = 0; ni < 2; ni++)
                acc[mi][ni] = __builtin_amdgcn_mfma_f32_16x16x32_bf16(af[mi], bfr[ni], acc[mi][ni], 0, 0, 0);
        __syncthreads();
    }
#pragma unroll
    for (int mi = 0; mi < 2; mi++)
#pragma unroll
        for (int ni = 0; ni < 2; ni++) {
            int row = m0 + wr * 32 + mi * 16 + (lane >> 4) * 4;
            int col = n0 + wc * 32 + ni * 16 + (lane & 15);
            float bias = bih[col];
#pragma unroll
            for (int i = 0; i < 4; i++)
                xp[(size_t)(row + i) * GA + col] = f2bf(acc[mi][ni][i] + bias);
        }
}

// ---------------- serial GRU: 7 WGs/batch (6 A-slices + 1 B) on ONE XCD ----------------
// blk = (b&7) + 8*(role + 7*(b>>3)), role 0..5 = A-slice (64 units), role 6 = B.
// XCD(blk%8) = b%8 for all roles.  Ring (both): u32 [b][slot 0..7][slice 0..5][64],
// word = (f16(h)<<16) | (t+1).
// A-WG thread roles: matvec 0..383 (row rr=tid%192, K-half kc=tid/192);
// gates 0..63 (unit u, LDS-only reads); xp loaders 128..319 (slot j=tid-128, 1 col);
// bprog reader tid==320; pollers 352..511 (exactly 1 u64 each: 5 remote slices x 32).
__global__ __launch_bounds__(512) void k_serial(
        const float* __restrict__ whhA, const float* __restrict__ bhhA,
        const float* __restrict__ wihB, const float* __restrict__ whhB,
        const float* __restrict__ bhhB, const u16* __restrict__ xp,
        const float* __restrict__ cpart, const float* __restrict__ h0a,
        const float* __restrict__ h0b, u32* hExF, u32* hExS, u32* bprog,
        float* __restrict__ yB) {
    const int blk = blockIdx.x, tid = threadIdx.x;
    const int q = blk >> 3;
    const int role = q % 7;
    const int b = (blk & 7) | ((q / 7) << 3);

    if (role < 6) {
        // ================= A-WG: slice s, units 64s..64s+63 =================
        __shared__ __align__(16) u32 hbuf[2][192];  // all 384 hA as f16 pairs, parity
        __shared__ float red[192][5];               // [row][kc] padded (stride 5: conflict-free)
        __shared__ u16 xpb[2][192];                 // xp slots, parity
        __shared__ int lbB, deadf, fastEn;
        const int s = role;
        const int rr = tid % 192, kc = tid / 192;   // matvec task for tid<384
        // weights: row rr (G = gate*384 + 64s + unit), K-half kc -> 96 packed u32
        u32 w[96];
        if (tid < 384) {
            const int G = (rr >> 6) * 384 + s * 64 + (rr & 63);
            const float* wr = whhA + (size_t)G * 384 + kc * 192;
#pragma unroll
            for (int i = 0; i < 96; i++) w[i] = packpair(wr[2 * i], wr[2 * i + 1]);
        }
        if (tid < 192) hbuf[0][tid] = packpair(h0a[b * 384 + 2 * tid], h0a[b * 384 + 2 * tid + 1]);
        // xp loader: slot j holds column (j>>6)*384 + s*64 + (j&63)
        const int j = tid - 128;
        const int xcol = (tid >= 128 && tid < 320) ? ((j >> 6) * 384 + s * 64 + (j & 63)) : 0;
        float hprA = 0, bh0 = 0, bh1 = 0, bh2 = 0;
        if (tid < 64) {
            hprA = h0a[b * 384 + s * 64 + tid];
            bh0 = bhhA[s * 64 + tid];
            bh1 = bhhA[384 + s * 64 + tid];
            bh2 = bhhA[768 + s * 64 + tid];
        }
        if (tid >= 128 && tid < 320) xpb[0][j] = xp[((size_t)b * S_LEN) * GA + xcol];
        if (tid == 0) { lbB = 0; deadf = 0; fastEn = 1; }
        __syncthreads();

        for (int t = 0; t < S_LEN; ++t) {
            const int p = t & 1, p2 = p ^ 1;
            const bool hasx = (t + 1 < S_LEN);
            u16 xq = 0;
            int lbn = -1;
            // PHASE1: pollers fetch 5 remote slices of h(t-1); loaders issue xp(t+1)
            if (tid >= 352) {
                if (t > 0) {
                    const int i = tid - 352, pi = i >> 5, k = i & 31;
                    const int ps = pi + (pi >= s ? 1 : 0);
                    const size_t woff = (((size_t)b * 8 + ((t - 1) & 7)) * 6 + ps) * 32 + k;
                    u64 v = poll64((const u64*)hExF + woff, (const u64*)hExS + woff,
                                   (u32)t & 0xffffu, t >= 2, &fastEn, &deadf);
                    hbuf[p][ps * 32 + k] = (((u32)v) >> 16) | (((u32)(v >> 32)) & 0xffff0000u);
                }
            } else if (tid >= 128 && tid < 320) {
                if (hasx) xq = xp[((size_t)b * S_LEN + t + 1) * GA + xcol];
            } else if (tid == 320) {
                if ((t & 3) == 0) lbn = (int)ald32(bprog + b);
            }
            wgbar();  // S1: hbuf[p] complete
            // PHASE2: matvec (one row-half per thread: 96 dot2)
            if (tid < 384) {
                const uint4* hb4 = (const uint4*)&hbuf[p][0] + kc * 24;
                float a0 = 0, a1 = 0;
#pragma unroll
                for (int c = 0; c < 24; c++) {
                    uint4 hc = hb4[c];
                    a0 = dot2p(w[4 * c + 0], hc.x, a0); a1 = dot2p(w[4 * c + 1], hc.y, a1);
                    a0 = dot2p(w[4 * c + 2], hc.z, a0); a1 = dot2p(w[4 * c + 3], hc.w, a1);
                }
                red[rr][kc] = a0 + a1;
            }
            if (hasx && tid >= 128 && tid < 320) xpb[p2][j] = xq;
            if (tid == 320 && lbn >= 0) lbB = lbn;
            wgbar();  // S2: red ready
            // PHASE3: gates + publish (LDS-only inputs; stores float)
            if (tid < 64) {
                float pr = red[tid][0] + red[tid][1] + bh0;
                float pz = red[64 + tid][0] + red[64 + tid][1] + bh1;
                float pn = red[128 + tid][0] + red[128 + tid][1] + bh2;
                float rg = sigm(bf2f(xpb[p][tid]) + pr);
                float zg = sigm(bf2f(xpb[p][64 + tid]) + pz);
                float ng = tanh_(bf2f(xpb[p][128 + tid]) + rg * pn);
                float hnew = (1.f - zg) * ng + zg * hprA;
                hprA = hnew;
                u16 hb16 = pack1(hnew);
                ((u16*)&hbuf[p2][0])[s * 64 + tid] = hb16;
                if (t - 7 > lbB && !deadf) {
                    int cnt = 0;
                    while ((int)ald32(bprog + b) < t - 7) {
                        if (++cnt > CAPP) { deadf = 1; break; }
                    }
                }
                const size_t poff = (((size_t)b * 8 + (t & 7)) * 6 + s) * 64 + tid;
                pub32(hExF + poff, hExS + poff, ((u32)hb16 << 16) | (u32)(t + 1));
            }
        }
    } else {
        // ================= B-WG: all 64 GRU-B units, hB fully local =================
        __shared__ __align__(16) u32 hbufA[192];
        __shared__ __align__(16) u16 hbB[2][64];
        __shared__ float redy[192][3];
        __shared__ float redh[192];
        __shared__ float cpl[32][192];
        __shared__ int deadB, fastEnB;
        const int r = (tid < 192) ? tid : tid - 192;
        const int kh = (tid < 192) ? 0 : 1;
        u32 wy[96];
        if (tid < 384) {
            const float* wr = wihB + (size_t)r * 512 + kh * 192;
#pragma unroll
            for (int i = 0; i < 96; i++) wy[i] = packpair(wr[2 * i], wr[2 * i + 1]);
        }
        u32 wb0[32], wb1[32];
        if (tid >= 384 && tid < 480) {
            const int rb = (tid - 384) * 2;
            const float* w0p = whhB + (size_t)rb * 64;
            const float* w1p = whhB + (size_t)(rb + 1) * 64;
#pragma unroll
            for (int i = 0; i < 32; i++) {
                wb0[i] = packpair(w0p[2 * i], w0p[2 * i + 1]);
                wb1[i] = packpair(w1p[2 * i], w1p[2 * i + 1]);
            }
        }
        for (int i = tid; i < 32 * 192; i += 512)
            cpl[i / 192][i % 192] = cpart[((size_t)b * 32) * 192 + i];
        float bB0 = 0, bB1 = 0, bB2 = 0, hprB = 0;
        if (tid < 64) {
            bB0 = bhhB[tid]; bB1 = bhhB[64 + tid]; bB2 = bhhB[128 + tid];
            hprB = h0b[b * 64 + tid];
            hbB[0][tid] = pack1(hprB);
        }
        if (tid == 0) { deadB = 0; fastEnB = 1; }
        __syncthreads();

        for (int tb = 0; tb < S_LEN; ++tb) {
            const int p = tb & 1, p2 = p ^ 1;
            // PHASE1: pollers tid 192..383 (1 u64 each: 6 slices x 32)
            if (tid >= 192 && tid < 384) {
                const int i = tid - 192, ps = i >> 5, k = i & 31;
                const size_t woff = (((size_t)b * 8 + (tb & 7)) * 6 + ps) * 32 + k;
                u64 v = poll64((const u64*)hExF + woff, (const u64*)hExS + woff,
                               (u32)(tb + 1) & 0xffffu, tb >= 1, &fastEnB, &deadB);
                hbufA[ps * 32 + k] = (((u32)v) >> 16) | (((u32)(v >> 32)) & 0xffff0000u);
            }
            wgbar();  // S1
            // PHASE2: matvecs
            if (tid < 384) {
                const uint4* hb4 = (const uint4*)&hbufA[0] + kh * 24;
                float a0 = 0, a1 = 0;
#pragma unroll
                for (int c = 0; c < 24; c++) {
                    uint4 hc = hb4[c];
                    a0 = dot2p(wy[4 * c + 0], hc.x, a0); a1 = dot2p(wy[4 * c + 1], hc.y, a1);
                    a0 = dot2p(wy[4 * c + 2], hc.z, a0); a1 = dot2p(wy[4 * c + 3], hc.w, a1);
                }
                redy[r][kh] = a0 + a1;
            } else if (tid < 480) {
                const uint4* hb4 = (const uint4*)&hbB[p][0];
                float a0 = 0, b0 = 0;
#pragma unroll
                for (int qq = 0; qq < 8; qq++) {
                    uint4 hc = hb4[qq];
                    a0 = dot2p(wb0[4 * qq + 0], hc.x, a0); a0 = dot2p(wb0[4 * qq + 1], hc.y, a0);
                    a0 = dot2p(wb0[4 * qq + 2], hc.z, a0); a0 = dot2p(wb0[4 * qq + 3], hc.w, a0);
                    b0 = dot2p(wb1[4 * qq + 0], hc.x, b0); b0 = dot2p(wb1[4 * qq + 1], hc.y, b0);
                    b0 = dot2p(wb1[4 * qq + 2], hc.z, b0); b0 = dot2p(wb1[4 * qq + 3], hc.w, b0);
                }
                const int rb = (tid - 384) * 2;
                redh[rb] = a0;
                redh[rb + 1] = b0;
            }
            wgbar();  // S2
            // PHASE3: gates + yB + progress
            if (tid < 64) {
                const int fr = tb / 160;
                float xr = redy[tid][0] + redy[tid][1] + cpl[fr][tid];
                float xz = redy[64 + tid][0] + redy[64 + tid][1] + cpl[fr][64 + tid];
                float xn = redy[128 + tid][0] + redy[128 + tid][1] + cpl[fr][128 + tid];
                float hr = redh[tid] + bB0;
                float hz = redh[64 + tid] + bB1;
                float hn = redh[128 + tid] + bB2;
                float rg = sigm(xr + hr);
                float zg = sigm(xz + hz);
                float ng = tanh_(xn + rg * hn);
                float hnew = (1.f - zg) * ng + zg * hprB;
                hprB = hnew;
                hbB[p2][tid] = pack1(hnew);
                yB[((size_t)b * S_LEN + tb) * UB + tid] = hnew;
                if (tid == 0) ast32(bprog + b, (u32)(tb + 1));
            }
        }
    }
}

// ---------------- dual FC + log_softmax ----------------
__global__ __launch_bounds__(256) void k_fc(const float* __restrict__ yB, const float* __restrict__ w1,
                                            const float* __restrict__ b1, const float* __restrict__ w2,
                                            const float* __restrict__ b2, const float* __restrict__ alpha,
                                            const float* __restrict__ beta, float* __restrict__ out) {
    __shared__ float yb[4][64];
    __shared__ float vb[4][256];
    int tid = threadIdx.x;
    size_t r0 = (size_t)blockIdx.x * 4;
    { int r = tid >> 6, k = tid & 63; yb[r][k] = yB[(r0 + r) * 64 + k]; }
    __syncthreads();
    int o = tid;
    float a1[4] = {0, 0, 0, 0}, a2[4] = {0, 0, 0, 0};
    for (int k = 0; k < 64; k += 4) {
        float4 u = *(const float4*)(w1 + o * 64 + k);
        float4 v = *(const float4*)(w2 + o * 64 + k);
#pragma unroll
        for (int r = 0; r < 4; r++) {
            float y0 = yb[r][k], y1 = yb[r][k + 1], y2 = yb[r][k + 2], y3 = yb[r][k + 3];
            a1[r] = fmaf(u.x, y0, fmaf(u.y, y1, fmaf(u.z, y2, fmaf(u.w, y3, a1[r]))));
            a2[r] = fmaf(v.x, y0, fmaf(v.y, y1, fmaf(v.z, y2, fmaf(v.w, y3, a2[r]))));
        }
    }
    float al = alpha[o], be = beta[o], c1 = b1[o], c2 = b2[o];
#pragma unroll
    for (int r = 0; r < 4; r++)
        vb[r][o] = al * tanh_(a1[r] + c1) + be * tanh_(a2[r] + c2);
    __syncthreads();
    int wv = tid >> 6, l = tid & 63;
    float x0 = vb[wv][l], x1 = vb[wv][64 + l], x2 = vb[wv][128 + l], x3 = vb[wv][192 + l];
    float m = fmaxf(fmaxf(x0, x1), fmaxf(x2, x3));
#pragma unroll
    for (int off = 1; off < 64; off <<= 1) m = fmaxf(m, __shfl_xor(m, off));
    float sum = __expf(x0 - m) + __expf(x1 - m) + __expf(x2 - m) + __expf(x3 - m);
#pragma unroll
    for (int off = 1; off < 64; off <<= 1) sum += __shfl_xor(sum, off);
    float lse = m + __logf(sum);
    float* po = out + (r0 + wv) * 256;
    po[l] = x0 - lse;
    po[64 + l] = x1 - lse;
    po[128 + l] = x2 - lse;
    po[192 + l] = x3 - lse;
}

extern "C" void kernel_launch(void* const* d_in, const int* in_sizes, int n_in,
                              void* d_out, int out_size, void* d_ws, size_t ws_size,
                              hipStream_t stream) {
    const float* features = (const float*)d_in[0];
    const int* periods = (const int*)d_in[1];
    const int* signals = (const int*)d_in[2];
    const float* gruA0 = (const float*)d_in[3];
    const float* gruB0 = (const float*)d_in[4];
    const float* period_emb = (const float*)d_in[5];
    const float* signal_emb = (const float*)d_in[6];
    const float* conv1_w = (const float*)d_in[7];
    const float* conv1_b = (const float*)d_in[8];
    const float* conv2_w = (const float*)d_in[9];
    const float* conv2_b = (const float*)d_in[10];
    const float* fd1_w = (const float*)d_in[11];
    const float* fd1_b = (const float*)d_in[12];
    const float* fd2_w = (const float*)d_in[13];
    const float* fd2_b = (const float*)d_in[14];
    const float* grua_wih = (const float*)d_in[15];
    const float* grua_whh = (const float*)d_in[16];
    const float* grua_bih = (const float*)d_in[17];
    const float* grua_bhh = (const float*)d_in[18];
    const float* grub_wih = (const float*)d_in[19];
    const float* grub_whh = (const float*)d_in[20];
    const float* grub_bih = (const float*)d_in[21];
    const float* grub_bhh = (const float*)d_in[22];
    const float* fc1_w = (const float*)d_in[23];
    const float* fc1_b = (const float*)d_in[24];
    const float* fc2_w = (const float*)d_in[25];
    const float* fc2_b = (const float*)d_in[26];
    const float* alpha = (const float*)d_in[27];
    const float* beta = (const float*)d_in[28];
    float* out = (float*)d_out;

    char* ws = (char*)d_ws;
    size_t off = 0;
    auto alloc = [&](size_t bytes) { void* p = ws + off; off += (bytes + 255) & ~(size_t)255; return p; };
    u16* xp = (u16*)alloc((size_t)16 * 5120 * 1152 * 2);
    u16* wihA = (u16*)alloc((size_t)1152 * 512 * 2);
    float* c1 = (float*)alloc((size_t)16 * 34 * 128 * 4);
    float* c2 = (float*)alloc((size_t)16 * 32 * 128 * 4);
    float* cc = (float*)alloc((size_t)16 * 32 * 128 * 4);
    float* cpart = (float*)alloc((size_t)16 * 32 * 192 * 4);
    float* yB = (float*)alloc((size_t)16 * 5120 * 64 * 4);
    u32* hExF = (u32*)alloc((size_t)RING_WORDS * 4);          // fast ring (L2-resident, sc0)
    u32* hExS = (u32*)alloc((size_t)(RING_WORDS + 256) * 4);  // slow ring (agent) + bprog
    u32* bprog = hExS + RING_WORDS;
    const int initN = 2 * RING_WORDS + 256;

    k_cvt<<<dim3(2304), dim3(256), 0, stream>>>(grua_wih, wihA);
    k_frame1<<<dim3(34, 16), dim3(128), 0, stream>>>(features, periods, period_emb, conv1_w, conv1_b, c1);
    k_frame2<<<dim3(32, 16), dim3(128), 0, stream>>>(c1, conv2_w, conv2_b, c2);
    k_fd<<<dim3(32, 16), dim3(128), 0, stream>>>(c2, fd1_w, fd1_b, fd2_w, fd2_b, cc);
    k_cpart<<<dim3(32, 16), dim3(192), 0, stream>>>(cc, grub_wih, grub_bih, cpart);
    k_init<<<dim3((initN + 255) / 256), dim3(256), 0, stream>>>(hExF, initN);
    k_gemm<<<dim3(1280, 18), dim3(256), 0, stream>>>(signals, signal_emb, cc, wihA, grua_bih, xp);
    k_serial<<<dim3(112), dim3(512), 0, stream>>>(grua_whh, grua_bhh, grub_wih, grub_whh, grub_bhh,
                                                  xp, cpart, gruA0, gruB0, hExF, hExS, bprog, yB);
    k_fc<<<dim3(20480), dim3(256), 0, stream>>>(yB, fc1_w, fc1_b, fc2_w, fc2_b, alpha, beta, out);
}

// Round 14
// 8306.323 us; speedup vs baseline: 2.0001x; 1.0549x over previous
//
#include <hip/hip_runtime.h>

typedef unsigned short u16;
typedef unsigned int u32;
typedef unsigned long long u64;
typedef __attribute__((ext_vector_type(8))) short bf16x8;
typedef __attribute__((ext_vector_type(4))) float f32x4;

#define S_LEN 5120
#define UB 64
#define GA 1152
#define CAPP (1 << 16)
#define FASTCAP 3000
#define RING_WORDS (16 * 8 * 12 * 32)

__device__ __forceinline__ float bf2f(u16 u) { return __uint_as_float(((u32)u) << 16); }
__device__ __forceinline__ u16 f2bf(float f) {
    u32 x = __float_as_uint(f);
    return (u16)((x + 0x7fffu + ((x >> 16) & 1u)) >> 16);
}
__device__ __forceinline__ float blo(u32 w) { return __uint_as_float(w << 16); }
__device__ __forceinline__ float bhi(u32 w) { return __uint_as_float(w & 0xffff0000u); }
__device__ __forceinline__ float sigm(float x) { return 1.f / (1.f + __expf(-x)); }
__device__ __forceinline__ float tanh_(float x) { float e = __expf(2.f * x); return 1.f - 2.f / (e + 1.f); }

#if __has_builtin(__builtin_amdgcn_fdot2)
typedef _Float16 h2v __attribute__((ext_vector_type(2)));
__device__ __forceinline__ float dot2p(u32 w, u32 h, float acc) {
    return __builtin_amdgcn_fdot2(__builtin_bit_cast(h2v, w), __builtin_bit_cast(h2v, h), acc, false);
}
__device__ __forceinline__ u32 packpair(float a, float b) {
    u16 x = __builtin_bit_cast(u16, (_Float16)a);
    u16 y = __builtin_bit_cast(u16, (_Float16)b);
    return (u32)x | ((u32)y << 16);
}
__device__ __forceinline__ u16 pack1(float a) { return __builtin_bit_cast(u16, (_Float16)a); }
#else
__device__ __forceinline__ float dot2p(u32 w, u32 h, float acc) {
    acc = fmaf(blo(w), blo(h), acc);
    return fmaf(bhi(w), bhi(h), acc);
}
__device__ __forceinline__ u32 packpair(float a, float b) { return (u32)f2bf(a) | ((u32)f2bf(b) << 16); }
__device__ __forceinline__ u16 pack1(float a) { return f2bf(a); }
#endif

__device__ __forceinline__ u64 ald64(const u64* p) {
    return __hip_atomic_load(p, __ATOMIC_RELAXED, __HIP_MEMORY_SCOPE_AGENT);
}
__device__ __forceinline__ u32 ald32(const u32* p) {
    return __hip_atomic_load(p, __ATOMIC_RELAXED, __HIP_MEMORY_SCOPE_AGENT);
}
__device__ __forceinline__ void ast32(u32* p, u32 v) {
    __hip_atomic_store(p, v, __ATOMIC_RELAXED, __HIP_MEMORY_SCOPE_AGENT);
}
// L1-bypassing load/store: same-XCD exchange through the shared L2
__device__ __forceinline__ u64 ld64_sc0(const u64* p) {
    u64 v;
    asm volatile("global_load_dwordx2 %0, %1, off sc0\n\ts_waitcnt vmcnt(0)"
                 : "=v"(v) : "v"(p) : "memory");
    return v;
}
__device__ __forceinline__ void st32_sc0(u32* p, u32 v) {
    asm volatile("global_store_dword %0, %1, off sc0" :: "v"(p), "v"(v) : "memory");
}
__device__ __forceinline__ void pub32(u32* fastp, u32* slowp, u32 v) {
    st32_sc0(fastp, v);
    ast32(slowp, v);   // mirror for cross-XCD fallback; floats (no barrier drain)
}
__device__ __forceinline__ u64 poll64(const u64* fastp, const u64* slowp, u32 tg,
                                      bool allowFast, int* fastEn, int* dead) {
    u64 v;
    if (allowFast && *fastEn) {
        for (int i = 0; i < FASTCAP; ++i) {
            v = ld64_sc0(fastp);
            if (((u32)v & 0xffffu) == tg && (((u32)(v >> 32)) & 0xffffu) == tg) return v;
        }
        *fastEn = 0;
    }
    int cnt = 0;
    for (;;) {
        v = ald64(slowp);
        if (((u32)v & 0xffffu) == tg && (((u32)(v >> 32)) & 0xffffu) == tg) return v;
        if (*dead || ++cnt > CAPP) { *dead = 1; return v; }
    }
}
// Raw WG barrier: drain ONLY LDS; global stores/loads float across.
__device__ __forceinline__ void wgbar() {
    __builtin_amdgcn_sched_barrier(0);
    asm volatile("s_waitcnt lgkmcnt(0)" ::: "memory");
    __builtin_amdgcn_s_barrier();
    __builtin_amdgcn_sched_barrier(0);
}

// ---------------- convert grua_wih to bf16 ----------------
__global__ __launch_bounds__(256) void k_cvt(const float* __restrict__ src, u16* __restrict__ dst) {
    int i = blockIdx.x * 256 + threadIdx.x;
    dst[i] = f2bf(src[i]);
}

// ---------------- frame-rate network ----------------
__global__ __launch_bounds__(128) void k_frame1(const float* __restrict__ features, const int* __restrict__ periods,
                                                const float* __restrict__ pemb, const float* __restrict__ w,
                                                const float* __restrict__ bias, float* __restrict__ c1) {
    __shared__ float fin[3][84];
    int t = blockIdx.x, b = blockIdx.y, o = threadIdx.x;
    for (int i = threadIdx.x; i < 252; i += 128) {
        int kk = i / 84, ci = i % 84, tt = t + kk;
        float v;
        if (ci < 20) v = features[(b * 36 + tt) * 20 + ci];
        else v = pemb[periods[b * 36 + tt] * 64 + (ci - 20)];
        fin[kk][ci] = v;
    }
    __syncthreads();
    float acc = bias[o];
    for (int kk = 0; kk < 3; kk++)
        for (int ci = 0; ci < 84; ci++)
            acc = fmaf(fin[kk][ci], w[o * 252 + ci * 3 + kk], acc);
    c1[(b * 34 + t) * 128 + o] = tanh_(acc);
}

__global__ __launch_bounds__(128) void k_frame2(const float* __restrict__ c1, const float* __restrict__ w,
                                                const float* __restrict__ bias, float* __restrict__ c2) {
    __shared__ float fin[3][128];
    int t = blockIdx.x, b = blockIdx.y, o = threadIdx.x;
    for (int i = threadIdx.x; i < 384; i += 128) {
        int kk = i >> 7, ci = i & 127;
        fin[kk][ci] = c1[(b * 34 + t + kk) * 128 + ci];
    }
    __syncthreads();
    float acc = bias[o];
    for (int kk = 0; kk < 3; kk++)
        for (int ci = 0; ci < 128; ci++)
            acc = fmaf(fin[kk][ci], w[o * 384 + ci * 3 + kk], acc);
    c2[(b * 32 + t) * 128 + o] = tanh_(acc);
}

__global__ __launch_bounds__(128) void k_fd(const float* __restrict__ c2, const float* __restrict__ w1,
                                            const float* __restrict__ b1, const float* __restrict__ w2,
                                            const float* __restrict__ b2, float* __restrict__ cc) {
    __shared__ float a0[128], a1s[128];
    int t = blockIdx.x, b = blockIdx.y, o = threadIdx.x;
    a0[o] = c2[(b * 32 + t) * 128 + o];
    __syncthreads();
    float acc = b1[o];
    for (int k = 0; k < 128; k++) acc = fmaf(a0[k], w1[o * 128 + k], acc);
    a1s[o] = tanh_(acc);
    __syncthreads();
    float acc2 = b2[o];
    for (int k = 0; k < 128; k++) acc2 = fmaf(a1s[k], w2[o * 128 + k], acc2);
    cc[(b * 32 + t) * 128 + o] = tanh_(acc2);
}

// cpart[b][fr][192] = grub_wih[:,384:512] @ c[b][fr] + grub_bih
__global__ __launch_bounds__(192) void k_cpart(const float* __restrict__ cc, const float* __restrict__ wihB,
                                               const float* __restrict__ bihB, float* __restrict__ cpart) {
    __shared__ float cl[128];
    int fr = blockIdx.x, b = blockIdx.y, o = threadIdx.x;
    if (o < 128) cl[o] = cc[(b * 32 + fr) * 128 + o];
    __syncthreads();
    float acc = bihB[o];
    for (int k = 0; k < 128; k++) acc = fmaf(cl[k], wihB[o * 512 + 384 + k], acc);
    cpart[((size_t)b * 32 + fr) * 192 + o] = acc;
}

// ---------------- init: clear BOTH rings + bprog with agent-scope stores ----------------
__global__ __launch_bounds__(256) void k_init(u32* base, int n) {
    int i = blockIdx.x * 256 + threadIdx.x;
    if (i < n) ast32(base + i, 0u);
}

// ---------------- GRU-A input projection GEMM ----------------
__global__ __launch_bounds__(256) void k_gemm(const int* __restrict__ signals, const float* __restrict__ semb,
                                              const float* __restrict__ c, const u16* __restrict__ wih,
                                              const float* __restrict__ bih, u16* __restrict__ xp) {
    __shared__ u16 As[64][40];
    __shared__ u16 Bs[64][40];
    int m0 = blockIdx.x * 64, n0 = blockIdx.y * 64;
    int tid = threadIdx.x;
    int r = tid >> 2, kc = tid & 3;
    int lane = tid & 63, wv = tid >> 6;
    int wr = wv >> 1, wc = wv & 1;
    int mrow = m0 + r;
    int b = mrow / S_LEN, s = mrow % S_LEN;
    const int* sigrow = signals + mrow * 3;
    const float* crow = c + ((size_t)(b * 32) + s / 160) * 128;
    f32x4 acc[2][2];
#pragma unroll
    for (int i = 0; i < 2; i++)
#pragma unroll
        for (int j = 0; j < 2; j++) { acc[i][j][0] = 0.f; acc[i][j][1] = 0.f; acc[i][j][2] = 0.f; acc[i][j][3] = 0.f; }
    for (int k0 = 0; k0 < 512; k0 += 32) {
        int k = k0 + kc * 8;
        float v[8];
        if (k < 384) {
            int idx = sigrow[k >> 7];
            const float* src = semb + idx * 128 + (k & 127);
#pragma unroll
            for (int j = 0; j < 8; j++) v[j] = src[j];
        } else {
            const float* src = crow + (k - 384);
#pragma unroll
            for (int j = 0; j < 8; j++) v[j] = src[j];
        }
        u32 pk[4];
#pragma unroll
        for (int j = 0; j < 4; j++) pk[j] = (u32)f2bf(v[2 * j]) | ((u32)f2bf(v[2 * j + 1]) << 16);
        *(uint4*)&As[r][kc * 8] = *(uint4*)pk;
        *(uint4*)&Bs[r][kc * 8] = *(const uint4*)&wih[(size_t)(n0 + r) * 512 + k];
        __syncthreads();
        bf16x8 af[2], bfr[2];
#pragma unroll
        for (int mi = 0; mi < 2; mi++) af[mi] = *(const bf16x8*)&As[wr * 32 + mi * 16 + (lane & 15)][(lane >> 4) * 8];
#pragma unroll
        for (int ni = 0; ni < 2; ni++) bfr[ni] = *(const bf16x8*)&Bs[wc * 32 + ni * 16 + (lane & 15)][(lane >> 4) * 8];
#pragma unroll
        for (int mi = 0; mi < 2; mi++)
#pragma unroll
            for (int ni = 0; ni < 2; ni++)
                acc[mi][ni] = __builtin_amdgcn_mfma_f32_16x16x32_bf16(af[mi], bfr[ni], acc[mi][ni], 0, 0, 0);
        __syncthreads();
    }
#pragma unroll
    for (int mi = 0; mi < 2; mi++)
#pragma unroll
        for (int ni = 0; ni < 2; ni++) {
            int row = m0 + wr * 32 + mi * 16 + (lane >> 4) * 4;
            int col = n0 + wc * 32 + ni * 16 + (lane & 15);
            float bias = bih[col];
#pragma unroll
            for (int i = 0; i < 4; i++)
                xp[(size_t)(row + i) * GA + col] = f2bf(acc[mi][ni][i] + bias);
        }
}

// ---------------- serial GRU: 13 WGs/batch (12 A-slices + 1 B) on ONE XCD ----------------
// blk = (b&7) + 8*(role + 13*(b>>3)), role 0..11 = A-slice (32 units), role 12 = B.
// XCD(blk%8) = b%8 for all roles.  Ring (both): u32 [b][slot 0..7][slice 0..11][32],
// word = (f16(h)<<16) | (t+1).
// A-WG thread roles: matvec 0..383 (row rr=tid%96, K-quarter kc=tid/96, 48 dot2);
// gates 0..31; xp loaders 128..223 (slot j=tid-128, 1 col); bprog reader tid==224;
// pollers 336..511 (exactly 1 u64 each: 11 remote slices x 16).
__global__ __launch_bounds__(512) void k_serial(
        const float* __restrict__ whhA, const float* __restrict__ bhhA,
        const float* __restrict__ wihB, const float* __restrict__ whhB,
        const float* __restrict__ bhhB, const u16* __restrict__ xp,
        const float* __restrict__ cpart, const float* __restrict__ h0a,
        const float* __restrict__ h0b, u32* hExF, u32* hExS, u32* bprog,
        float* __restrict__ yB) {
    const int blk = blockIdx.x, tid = threadIdx.x;
    const int q = blk >> 3;
    const int role = q % 13;
    const int b = (blk & 7) | ((q / 13) << 3);

    if (role < 12) {
        // ================= A-WG: slice s, units 32s..32s+31 =================
        __shared__ __align__(16) u32 hbuf[2][192];  // all 384 hA as f16 pairs, parity
        __shared__ float red[96][5];                // [row][kc] padded (stride 5)
        __shared__ u16 xpb[2][96];                  // xp slots, parity
        __shared__ int lbB, deadf, fastEn;
        const int s = role;
        const int rr = tid % 96, kc = tid / 96;     // matvec task for tid<384
        // weights: row rr (G = gate*384 + 32s + unit), K-quarter kc -> 48 packed u32
        u32 w[48];
        if (tid < 384) {
            const int G = (rr >> 5) * 384 + s * 32 + (rr & 31);
            const float* wr = whhA + (size_t)G * 384 + kc * 96;
#pragma unroll
            for (int i = 0; i < 48; i++) w[i] = packpair(wr[2 * i], wr[2 * i + 1]);
        }
        if (tid < 192) hbuf[0][tid] = packpair(h0a[b * 384 + 2 * tid], h0a[b * 384 + 2 * tid + 1]);
        // xp loader: slot j holds column (j>>5)*384 + s*32 + (j&31)
        const int j = tid - 128;
        const int xcol = (tid >= 128 && tid < 224) ? ((j >> 5) * 384 + s * 32 + (j & 31)) : 0;
        float hprA = 0, bh0 = 0, bh1 = 0, bh2 = 0;
        if (tid < 32) {
            hprA = h0a[b * 384 + s * 32 + tid];
            bh0 = bhhA[s * 32 + tid];
            bh1 = bhhA[384 + s * 32 + tid];
            bh2 = bhhA[768 + s * 32 + tid];
        }
        if (tid >= 128 && tid < 224) xpb[0][j] = xp[((size_t)b * S_LEN) * GA + xcol];
        if (tid == 0) { lbB = 0; deadf = 0; fastEn = 1; }
        __syncthreads();

        for (int t = 0; t < S_LEN; ++t) {
            const int p = t & 1, p2 = p ^ 1;
            const bool hasx = (t + 1 < S_LEN);
            u16 xq = 0;
            int lbn = -1;
            // PHASE1: pollers fetch 11 remote slices of h(t-1); loaders issue xp(t+1)
            if (tid >= 336) {
                if (t > 0) {
                    const int i = tid - 336, pi = i >> 4, k = i & 15;
                    const int ps = pi + (pi >= s ? 1 : 0);
                    const size_t woff = (((size_t)b * 8 + ((t - 1) & 7)) * 12 + ps) * 16 + k;
                    u64 v = poll64((const u64*)hExF + woff, (const u64*)hExS + woff,
                                   (u32)t & 0xffffu, t >= 2, &fastEn, &deadf);
                    hbuf[p][ps * 16 + k] = (((u32)v) >> 16) | (((u32)(v >> 32)) & 0xffff0000u);
                }
            } else if (tid >= 128 && tid < 224) {
                if (hasx) xq = xp[((size_t)b * S_LEN + t + 1) * GA + xcol];
            } else if (tid == 224) {
                if ((t & 3) == 0) lbn = (int)ald32(bprog + b);
            }
            wgbar();  // S1: hbuf[p] complete
            // PHASE2: matvec (one row-quarter per thread: 48 dot2)
            if (tid < 384) {
                const uint4* hb4 = (const uint4*)&hbuf[p][0] + kc * 12;
                float a0 = 0, a1 = 0;
#pragma unroll
                for (int c = 0; c < 12; c++) {
                    uint4 hc = hb4[c];
                    a0 = dot2p(w[4 * c + 0], hc.x, a0); a1 = dot2p(w[4 * c + 1], hc.y, a1);
                    a0 = dot2p(w[4 * c + 2], hc.z, a0); a1 = dot2p(w[4 * c + 3], hc.w, a1);
                }
                red[rr][kc] = a0 + a1;
            }
            if (hasx && tid >= 128 && tid < 224) xpb[p2][j] = xq;
            if (tid == 224 && lbn >= 0) lbB = lbn;
            wgbar();  // S2: red ready
            // PHASE3: gates + publish (LDS-only inputs; stores float)
            if (tid < 32) {
                float pr = red[tid][0] + red[tid][1] + red[tid][2] + red[tid][3] + bh0;
                float pz = red[32 + tid][0] + red[32 + tid][1] + red[32 + tid][2] + red[32 + tid][3] + bh1;
                float pn = red[64 + tid][0] + red[64 + tid][1] + red[64 + tid][2] + red[64 + tid][3] + bh2;
                float rg = sigm(bf2f(xpb[p][tid]) + pr);
                float zg = sigm(bf2f(xpb[p][32 + tid]) + pz);
                float ng = tanh_(bf2f(xpb[p][64 + tid]) + rg * pn);
                float hnew = (1.f - zg) * ng + zg * hprA;
                hprA = hnew;
                u16 hb16 = pack1(hnew);
                ((u16*)&hbuf[p2][0])[s * 32 + tid] = hb16;
                if (t - 7 > lbB && !deadf) {
                    int cnt = 0;
                    while ((int)ald32(bprog + b) < t - 7) {
                        if (++cnt > CAPP) { deadf = 1; break; }
                    }
                }
                const size_t poff = (((size_t)b * 8 + (t & 7)) * 12 + s) * 32 + tid;
                pub32(hExF + poff, hExS + poff, ((u32)hb16 << 16) | (u32)(t + 1));
            }
        }
    } else {
        // ================= B-WG: all 64 GRU-B units, hB fully local =================
        __shared__ __align__(16) u32 hbufA[192];
        __shared__ __align__(16) u16 hbB[2][64];
        __shared__ float redy[192][3];
        __shared__ float redh[192];
        __shared__ float cpl[32][192];
        __shared__ int deadB, fastEnB;
        const int r = (tid < 192) ? tid : tid - 192;
        const int kh = (tid < 192) ? 0 : 1;
        u32 wy[96];
        if (tid < 384) {
            const float* wr = wihB + (size_t)r * 512 + kh * 192;
#pragma unroll
            for (int i = 0; i < 96; i++) wy[i] = packpair(wr[2 * i], wr[2 * i + 1]);
        }
        u32 wb0[32], wb1[32];
        if (tid >= 384 && tid < 480) {
            const int rb = (tid - 384) * 2;
            const float* w0p = whhB + (size_t)rb * 64;
            const float* w1p = whhB + (size_t)(rb + 1) * 64;
#pragma unroll
            for (int i = 0; i < 32; i++) {
                wb0[i] = packpair(w0p[2 * i], w0p[2 * i + 1]);
                wb1[i] = packpair(w1p[2 * i], w1p[2 * i + 1]);
            }
        }
        for (int i = tid; i < 32 * 192; i += 512)
            cpl[i / 192][i % 192] = cpart[((size_t)b * 32) * 192 + i];
        float bB0 = 0, bB1 = 0, bB2 = 0, hprB = 0;
        if (tid < 64) {
            bB0 = bhhB[tid]; bB1 = bhhB[64 + tid]; bB2 = bhhB[128 + tid];
            hprB = h0b[b * 64 + tid];
            hbB[0][tid] = pack1(hprB);
        }
        if (tid == 0) { deadB = 0; fastEnB = 1; }
        __syncthreads();

        for (int tb = 0; tb < S_LEN; ++tb) {
            const int p = tb & 1, p2 = p ^ 1;
            // PHASE1: pollers tid 192..383 (1 u64 each: 12 slices x 16)
            if (tid >= 192 && tid < 384) {
                const int i = tid - 192, ps = i >> 4, k = i & 15;
                const size_t woff = (((size_t)b * 8 + (tb & 7)) * 12 + ps) * 16 + k;
                u64 v = poll64((const u64*)hExF + woff, (const u64*)hExS + woff,
                               (u32)(tb + 1) & 0xffffu, tb >= 1, &fastEnB, &deadB);
                hbufA[ps * 16 + k] = (((u32)v) >> 16) | (((u32)(v >> 32)) & 0xffff0000u);
            }
            wgbar();  // S1
            // PHASE2: matvecs
            if (tid < 384) {
                const uint4* hb4 = (const uint4*)&hbufA[0] + kh * 24;
                float a0 = 0, a1 = 0;
#pragma unroll
                for (int c = 0; c < 24; c++) {
                    uint4 hc = hb4[c];
                    a0 = dot2p(wy[4 * c + 0], hc.x, a0); a1 = dot2p(wy[4 * c + 1], hc.y, a1);
                    a0 = dot2p(wy[4 * c + 2], hc.z, a0); a1 = dot2p(wy[4 * c + 3], hc.w, a1);
                }
                redy[r][kh] = a0 + a1;
            } else if (tid < 480) {
                const uint4* hb4 = (const uint4*)&hbB[p][0];
                float a0 = 0, b0 = 0;
#pragma unroll
                for (int qq = 0; qq < 8; qq++) {
                    uint4 hc = hb4[qq];
                    a0 = dot2p(wb0[4 * qq + 0], hc.x, a0); a0 = dot2p(wb0[4 * qq + 1], hc.y, a0);
                    a0 = dot2p(wb0[4 * qq + 2], hc.z, a0); a0 = dot2p(wb0[4 * qq + 3], hc.w, a0);
                    b0 = dot2p(wb1[4 * qq + 0], hc.x, b0); b0 = dot2p(wb1[4 * qq + 1], hc.y, b0);
                    b0 = dot2p(wb1[4 * qq + 2], hc.z, b0); b0 = dot2p(wb1[4 * qq + 3], hc.w, b0);
                }
                const int rb = (tid - 384) * 2;
                redh[rb] = a0;
                redh[rb + 1] = b0;
            }
            wgbar();  // S2
            // PHASE3: gates + yB + progress
            if (tid < 64) {
                const int fr = tb / 160;
                float xr = redy[tid][0] + redy[tid][1] + cpl[fr][tid];
                float xz = redy[64 + tid][0] + redy[64 + tid][1] + cpl[fr][64 + tid];
                float xn = redy[128 + tid][0] + redy[128 + tid][1] + cpl[fr][128 + tid];
                float hr = redh[tid] + bB0;
                float hz = redh[64 + tid] + bB1;
                float hn = redh[128 + tid] + bB2;
                float rg = sigm(xr + hr);
                float zg = sigm(xz + hz);
                float ng = tanh_(xn + rg * hn);
                float hnew = (1.f - zg) * ng + zg * hprB;
                hprB = hnew;
                hbB[p2][tid] = pack1(hnew);
                yB[((size_t)b * S_LEN + tb) * UB + tid] = hnew;
                if (tid == 0) ast32(bprog + b, (u32)(tb + 1));
            }
        }
    }
}

// ---------------- dual FC + log_softmax ----------------
__global__ __launch_bounds__(256) void k_fc(const float* __restrict__ yB, const float* __restrict__ w1,
                                            const float* __restrict__ b1, const float* __restrict__ w2,
                                            const float* __restrict__ b2, const float* __restrict__ alpha,
                                            const float* __restrict__ beta, float* __restrict__ out) {
    __shared__ float yb[4][64];
    __shared__ float vb[4][256];
    int tid = threadIdx.x;
    size_t r0 = (size_t)blockIdx.x * 4;
    { int r = tid >> 6, k = tid & 63; yb[r][k] = yB[(r0 + r) * 64 + k]; }
    __syncthreads();
    int o = tid;
    float a1[4] = {0, 0, 0, 0}, a2[4] = {0, 0, 0, 0};
    for (int k = 0; k < 64; k += 4) {
        float4 u = *(const float4*)(w1 + o * 64 + k);
        float4 v = *(const float4*)(w2 + o * 64 + k);
#pragma unroll
        for (int r = 0; r < 4; r++) {
            float y0 = yb[r][k], y1 = yb[r][k + 1], y2 = yb[r][k + 2], y3 = yb[r][k + 3];
            a1[r] = fmaf(u.x, y0, fmaf(u.y, y1, fmaf(u.z, y2, fmaf(u.w, y3, a1[r]))));
            a2[r] = fmaf(v.x, y0, fmaf(v.y, y1, fmaf(v.z, y2, fmaf(v.w, y3, a2[r]))));
        }
    }
    float al = alpha[o], be = beta[o], c1 = b1[o], c2 = b2[o];
#pragma unroll
    for (int r = 0; r < 4; r++)
        vb[r][o] = al * tanh_(a1[r] + c1) + be * tanh_(a2[r] + c2);
    __syncthreads();
    int wv = tid >> 6, l = tid & 63;
    float x0 = vb[wv][l], x1 = vb[wv][64 + l], x2 = vb[wv][128 + l], x3 = vb[wv][192 + l];
    float m = fmaxf(fmaxf(x0, x1), fmaxf(x2, x3));
#pragma unroll
    for (int off = 1; off < 64; off <<= 1) m = fmaxf(m, __shfl_xor(m, off));
    float sum = __expf(x0 - m) + __expf(x1 - m) + __expf(x2 - m) + __expf(x3 - m);
#pragma unroll
    for (int off = 1; off < 64; off <<= 1) sum += __shfl_xor(sum, off);
    float lse = m + __logf(sum);
    float* po = out + (r0 + wv) * 256;
    po[l] = x0 - lse;
    po[64 + l] = x1 - lse;
    po[128 + l] = x2 - lse;
    po[192 + l] = x3 - lse;
}

extern "C" void kernel_launch(void* const* d_in, const int* in_sizes, int n_in,
                              void* d_out, int out_size, void* d_ws, size_t ws_size,
                              hipStream_t stream) {
    const float* features = (const float*)d_in[0];
    const int* periods = (const int*)d_in[1];
    const int* signals = (const int*)d_in[2];
    const float* gruA0 = (const float*)d_in[3];
    const float* gruB0 = (const float*)d_in[4];
    const float* period_emb = (const float*)d_in[5];
    const float* signal_emb = (const float*)d_in[6];
    const float* conv1_w = (const float*)d_in[7];
    const float* conv1_b = (const float*)d_in[8];
    const float* conv2_w = (const float*)d_in[9];
    const float* conv2_b = (const float*)d_in[10];
    const float* fd1_w = (const float*)d_in[11];
    const float* fd1_b = (const float*)d_in[12];
    const float* fd2_w = (const float*)d_in[13];
    const float* fd2_b = (const float*)d_in[14];
    const float* grua_wih = (const float*)d_in[15];
    const float* grua_whh = (const float*)d_in[16];
    const float* grua_bih = (const float*)d_in[17];
    const float* grua_bhh = (const float*)d_in[18];
    const float* grub_wih = (const float*)d_in[19];
    const float* grub_whh = (const float*)d_in[20];
    const float* grub_bih = (const float*)d_in[21];
    const float* grub_bhh = (const float*)d_in[22];
    const float* fc1_w = (const float*)d_in[23];
    const float* fc1_b = (const float*)d_in[24];
    const float* fc2_w = (const float*)d_in[25];
    const float* fc2_b = (const float*)d_in[26];
    const float* alpha = (const float*)d_in[27];
    const float* beta = (const float*)d_in[28];
    float* out = (float*)d_out;

    char* ws = (char*)d_ws;
    size_t off = 0;
    auto alloc = [&](size_t bytes) { void* p = ws + off; off += (bytes + 255) & ~(size_t)255; return p; };
    u16* xp = (u16*)alloc((size_t)16 * 5120 * 1152 * 2);
    u16* wihA = (u16*)alloc((size_t)1152 * 512 * 2);
    float* c1 = (float*)alloc((size_t)16 * 34 * 128 * 4);
    float* c2 = (float*)alloc((size_t)16 * 32 * 128 * 4);
    float* cc = (float*)alloc((size_t)16 * 32 * 128 * 4);
    float* cpart = (float*)alloc((size_t)16 * 32 * 192 * 4);
    float* yB = (float*)alloc((size_t)16 * 5120 * 64 * 4);
    u32* hExF = (u32*)alloc((size_t)RING_WORDS * 4);          // fast ring (L2-resident, sc0)
    u32* hExS = (u32*)alloc((size_t)(RING_WORDS + 256) * 4);  // slow ring (agent) + bprog
    u32* bprog = hExS + RING_WORDS;
    const int initN = 2 * RING_WORDS + 256;

    k_cvt<<<dim3(2304), dim3(256), 0, stream>>>(grua_wih, wihA);
    k_frame1<<<dim3(34, 16), dim3(128), 0, stream>>>(features, periods, period_emb, conv1_w, conv1_b, c1);
    k_frame2<<<dim3(32, 16), dim3(128), 0, stream>>>(c1, conv2_w, conv2_b, c2);
    k_fd<<<dim3(32, 16), dim3(128), 0, stream>>>(c2, fd1_w, fd1_b, fd2_w, fd2_b, cc);
    k_cpart<<<dim3(32, 16), dim3(192), 0, stream>>>(cc, grub_wih, grub_bih, cpart);
    k_init<<<dim3((initN + 255) / 256), dim3(256), 0, stream>>>(hExF, initN);
    k_gemm<<<dim3(1280, 18), dim3(256), 0, stream>>>(signals, signal_emb, cc, wihA, grua_bih, xp);
    k_serial<<<dim3(208), dim3(512), 0, stream>>>(grua_whh, grua_bhh, grub_wih, grub_whh, grub_bhh,
                                                  xp, cpart, gruA0, gruB0, hExF, hExS, bprog, yB);
    k_fc<<<dim3(20480), dim3(256), 0, stream>>>(yB, fc1_w, fc1_b, fc2_w, fc2_b, alpha, beta, out);
}